// Round 4
// baseline (10593.517 us; speedup 1.0000x reference)
//
#include <hip/hip_runtime.h>
#include <hip/hip_bf16.h>
#include <math.h>

// Problem dims
#define PP 400
#define QQ 30
#define BB 32
#define EE 300
#define HH 300
#define FF 300
#define AA 30
#define LL 2

typedef unsigned short ushort_t;
typedef unsigned int uint_t;
typedef __attribute__((ext_vector_type(8))) short short8;
typedef __attribute__((ext_vector_type(16))) float floatx16;

// ---------------------------------------------------------------------------
// Embedding gather: out[row, e] = embed[tok[row], e]
__global__ void gather_embed(const int* __restrict__ tok,
                             const float* __restrict__ embed,
                             float* __restrict__ out, int n_tok) {
    int i = blockIdx.x * blockDim.x + threadIdx.x;
    int n = n_tok * EE;
    if (i >= n) return;
    int row = i / EE, e = i - row * EE;
    out[i] = embed[(size_t)tok[row] * EE + e];
}

// ---------------------------------------------------------------------------
// C[M,N] = A[M,K] @ Bw[N,K]^T + bias[N], optional relu.
#define BM 64
#define BN 64
#define BK 16
__global__ void gemm_nt_bias(const float* __restrict__ A,
                             const float* __restrict__ Bw,
                             const float* __restrict__ bias,
                             float* __restrict__ C,
                             int M, int N, int K, int relu) {
    __shared__ float As[BK][BM];
    __shared__ float Bs[BK][BN];
    int tid = threadIdx.x;
    int row0 = blockIdx.y * BM;
    int col0 = blockIdx.x * BN;
    int tx = tid & 15, ty = tid >> 4;
    int lm = tid >> 2;          // 0..63
    int lk = (tid & 3) * 4;     // 0,4,8,12
    float acc[4][4] = {{0.f}};
    for (int k0 = 0; k0 < K; k0 += BK) {
        float4 av = make_float4(0.f, 0.f, 0.f, 0.f);
        int ar = row0 + lm;
        int kk = k0 + lk;
        if (ar < M) {
            if (kk + 3 < K) {
                av = *(const float4*)(A + (size_t)ar * K + kk);
            } else {
                float t0 = (kk + 0 < K) ? A[(size_t)ar * K + kk + 0] : 0.f;
                float t1 = (kk + 1 < K) ? A[(size_t)ar * K + kk + 1] : 0.f;
                float t2 = (kk + 2 < K) ? A[(size_t)ar * K + kk + 2] : 0.f;
                float t3 = (kk + 3 < K) ? A[(size_t)ar * K + kk + 3] : 0.f;
                av = make_float4(t0, t1, t2, t3);
            }
        }
        As[lk + 0][lm] = av.x; As[lk + 1][lm] = av.y;
        As[lk + 2][lm] = av.z; As[lk + 3][lm] = av.w;

        float4 bv = make_float4(0.f, 0.f, 0.f, 0.f);
        int br = col0 + lm;
        if (br < N) {
            if (kk + 3 < K) {
                bv = *(const float4*)(Bw + (size_t)br * K + kk);
            } else {
                float t0 = (kk + 0 < K) ? Bw[(size_t)br * K + kk + 0] : 0.f;
                float t1 = (kk + 1 < K) ? Bw[(size_t)br * K + kk + 1] : 0.f;
                float t2 = (kk + 2 < K) ? Bw[(size_t)br * K + kk + 2] : 0.f;
                float t3 = (kk + 3 < K) ? Bw[(size_t)br * K + kk + 3] : 0.f;
                bv = make_float4(t0, t1, t2, t3);
            }
        }
        Bs[lk + 0][lm] = bv.x; Bs[lk + 1][lm] = bv.y;
        Bs[lk + 2][lm] = bv.z; Bs[lk + 3][lm] = bv.w;
        __syncthreads();
        #pragma unroll
        for (int k = 0; k < BK; k++) {
            float a[4], b[4];
            #pragma unroll
            for (int i = 0; i < 4; i++) a[i] = As[k][ty * 4 + i];
            #pragma unroll
            for (int j = 0; j < 4; j++) b[j] = Bs[k][tx * 4 + j];
            #pragma unroll
            for (int i = 0; i < 4; i++) {
                #pragma unroll
                for (int j = 0; j < 4; j++) acc[i][j] += a[i] * b[j];
            }
        }
        __syncthreads();
    }
    #pragma unroll
    for (int i = 0; i < 4; i++) {
        int r = row0 + ty * 4 + i;
        if (r >= M) continue;
        #pragma unroll
        for (int j = 0; j < 4; j++) {
            int c = col0 + tx * 4 + j;
            if (c >= N) continue;
            float v = acc[i][j] + bias[c];
            if (relu) v = fmaxf(v, 0.f);
            C[(size_t)r * N + c] = v;
        }
    }
}

// ---------------------------------------------------------------------------
// scores + softmax over q per (p,b)
__global__ void scores_softmax(const float* __restrict__ ffp,
                               const float* __restrict__ ffq,
                               const float* __restrict__ p_mask,
                               const float* __restrict__ q_mask,
                               float* __restrict__ weights) {
    int blk = blockIdx.x;          // p*BB + b
    int p = blk / BB, b = blk - p * BB;
    __shared__ float fp[FF];
    __shared__ float sq[QQ];
    for (int f = threadIdx.x; f < FF; f += blockDim.x)
        fp[f] = ffp[(size_t)(p * BB + b) * FF + f];
    __syncthreads();
    int q = threadIdx.x;
    if (q < QQ) {
        const float* fq = ffq + (size_t)(q * BB + b) * FF;
        float s = 0.f;
        for (int f = 0; f < FF; f++) s += fp[f] * fq[f];
        s *= p_mask[p * BB + b] * q_mask[q * BB + b];
        sq[q] = s;
    }
    __syncthreads();
    if (q < QQ) {
        float m = -INFINITY;
        for (int k = 0; k < QQ; k++) m = fmaxf(m, sq[k]);
        float sum = 0.f;
        for (int k = 0; k < QQ; k++) sum += expf(sq[k] - m);
        weights[(size_t)b * PP * QQ + p * QQ + q] = expf(sq[q] - m) / sum;
    }
}

// ---------------------------------------------------------------------------
__global__ void align_concat(const float* __restrict__ weights,
                             const float* __restrict__ q_emb,
                             const float* __restrict__ p_emb,
                             float* __restrict__ x0) {
    int blk = blockIdx.x;          // p*BB + b
    int p = blk / BB, b = blk - p * BB;
    __shared__ float w[QQ];
    if (threadIdx.x < QQ)
        w[threadIdx.x] = weights[(size_t)b * PP * QQ + p * QQ + threadIdx.x];
    __syncthreads();
    for (int e = threadIdx.x; e < EE; e += blockDim.x) {
        float acc = 0.f;
        for (int q = 0; q < QQ; q++)
            acc += w[q] * q_emb[(size_t)(q * BB + b) * EE + e];
        size_t base = (size_t)(p * BB + b) * (2 * EE);
        x0[base + e] = p_emb[(size_t)(p * BB + b) * EE + e];
        x0[base + EE + e] = acc;
    }
}

// ---------------------------------------------------------------------------
// w_hh fp32 [4][900][300] -> bf16 (RNE) same layout
__global__ void convert_whh_bf16(const float* __restrict__ w,
                                 ushort_t* __restrict__ o) {
    int i = blockIdx.x * blockDim.x + threadIdx.x;
    if (i >= 4 * 900 * 300) return;
    uint_t u = __float_as_uint(w[i]);
    uint_t r = (u + 0x7fffu + ((u >> 16) & 1u)) >> 16;
    o[i] = (ushort_t)r;
}

// zero h double-buffers (both layers, bf16-pair dwords) and group counters
#define HBUF_DWORDS (2 * 2 * 2 * 32 * 156)   // [L][buf][dir][b][156]
__global__ void init_gru(uint_t* __restrict__ hbuf, int* __restrict__ cnt) {
    int i = blockIdx.x * blockDim.x + threadIdx.x;
    if (i < HBUF_DWORDS) hbuf[i] = 0u;
    if (i < 2 * 2 * 16) cnt[i] = 0;
}

// ---------------------------------------------------------------------------
// Persistent BiGRU layer, MFMA recurrence. Grid = 20 blocks x 192 threads:
// group = dir (10 blocks each). Block bi owns j-slice [j0, j0+30) for ALL 32
// batches; per step computes gh[3 gates x 30 j x 32 b] = W_slice @ h via
// v_mfma_f32_32x32x16_bf16. Wave g (=gate) holds its 32-row M-tile's 19
// K-chunk A-fragments RESIDENT in VGPRs (loaded once) -- zero weight LDS
// traffic in the loop. h transported between blocks as packed-bf16 dwords
// through relaxed agent-scope atomics (fence-free protocol from R3); each
// block keeps its own j-slice of h in fp32 LDS so the z*h recurrence chain
// never quantizes.
#define GRP 10
__global__ __launch_bounds__(192, 1) void gru_layer(
        const float* __restrict__ xp_all, // [2 dir][400][32][900] contiguous
        const ushort_t* __restrict__ wbf, // [2 dir][900][300] bf16, this layer
        const float* __restrict__ bhh,    // [2 dir][900], this layer
        uint_t* __restrict__ hbuf,        // [2 buf][2 dir][32][156] dwords
        int* __restrict__ cnts,           // [2 dir][16], this layer
        float* __restrict__ out) {        // [400][32][600]
    int dir = blockIdx.x / GRP;
    int bi  = blockIdx.x - dir * GRP;
    int j0  = bi * 30;
    const float* xp = xp_all + (size_t)dir * (400 * 32 * 900);
    int tid = threadIdx.x;
    int lane = tid & 63;
    int g = tid >> 6;                 // wave id == gate (0=r,1=z,2=n)
    int* cnt = cnts + dir * 16;

    __shared__ ushort_t sh2[32][312]; // h bf16, [batch][k], k padded 300->312
    __shared__ float sgh[3][32][32];  // gh f32 [gate][row][batch]
    __shared__ float shp[30][32];     // private fp32 h [jj][batch]
    __shared__ float sbias[3][32];

    for (int i = tid; i < 30 * 32; i += 192) ((float*)shp)[i] = 0.f;
    if (tid < 96) {
        int gg = tid >> 5, m = tid & 31;
        sbias[gg][m] = (m < 30) ? bhh[dir * 900 + gg * 300 + j0 + m] : 0.f;
    }

    // A-fragments (weights) resident in registers: 19 K-chunks of 16.
    // lane layout for 32x32x16 bf16 A: m = lane&31, k = (lane>>5)*8 + e.
    short8 afrag[19];
    {
        int m = lane & 31, half = lane >> 5;
        const ushort_t* wrow =
            wbf + (size_t)dir * 270000 + (size_t)(g * 300 + j0 + m) * 300;
        for (int c = 0; c < 19; c++) {
            int k0 = c * 16 + half * 8;
            short8 f;
            #pragma unroll
            for (int e = 0; e < 8; e++) {
                int k = k0 + e;
                f[e] = (short)((m < 30 && k < 300) ? wrow[k] : (ushort_t)0);
            }
            afrag[c] = f;
        }
    }
    __syncthreads();

    for (int s = 0; s < PP; s++) {
        int te = dir ? (PP - 1 - s) : s;
        // prefetch xp gate inputs for this thread's (jj-pair, b) items
        // (independent of h; completes during the poll)
        float2 xf[3][3];
        {
            int it = 0;
            for (int o = tid; o < 480; o += 192, it++) {
                int jp = o >> 5, b = o & 31;
                const float* base =
                    xp + ((size_t)te * 32 + b) * 900 + j0 + jp * 2;
                xf[it][0] = *(const float2*)(base);
                xf[it][1] = *(const float2*)(base + 300);
                xf[it][2] = *(const float2*)(base + 600);
            }
        }
        // wait for previous step's h (relaxed poll, fence-free)
        if (s > 0) {
            if (tid == 0) {
                while (__hip_atomic_load(cnt, __ATOMIC_RELAXED,
                                         __HIP_MEMORY_SCOPE_AGENT) < GRP * s)
                    __builtin_amdgcn_s_sleep(1);
            }
            __syncthreads();
        }
        // stage h: global dwords -> LDS (identical linear layout)
        {
            const uint_t* src = hbuf + (size_t)(s & 1) * (2 * 32 * 156)
                                + (size_t)dir * (32 * 156);
            uint_t* dst = (uint_t*)sh2;
            for (int d = tid; d < 32 * 156; d += 192)
                dst[d] = __hip_atomic_load(&src[d], __ATOMIC_RELAXED,
                                           __HIP_MEMORY_SCOPE_AGENT);
        }
        __syncthreads();
        // MFMA: this wave's gate tile, A resident, B from LDS (ds_read_b128)
        floatx16 acc;
        #pragma unroll
        for (int r = 0; r < 16; r++) acc[r] = 0.f;
        {
            int n = lane & 31, half = lane >> 5;
            #pragma unroll
            for (int c = 0; c < 19; c++) {
                short8 bf = *(const short8*)&sh2[n][c * 16 + half * 8];
                acc = __builtin_amdgcn_mfma_f32_32x32x16_bf16(
                    afrag[c], bf, acc, 0, 0, 0);
            }
        }
        // C/D layout: col = lane&31, row = (r&3) + 8*(r>>2) + 4*(lane>>5)
        {
            int col = lane & 31, rbase = 4 * (lane >> 5);
            #pragma unroll
            for (int r = 0; r < 16; r++) {
                int row = (r & 3) + 8 * (r >> 2) + rbase;
                sgh[g][row][col] = acc[r];
            }
        }
        __syncthreads();
        // gates + h update + publish (packed bf16 pairs)
        {
            uint_t* dstbuf = hbuf + (size_t)((s + 1) & 1) * (2 * 32 * 156)
                             + (size_t)dir * (32 * 156);
            int it = 0;
            for (int o = tid; o < 480; o += 192, it++) {
                int jp = o >> 5, b = o & 31;
                int jj = jp * 2;
                float2 xr = xf[it][0], xz = xf[it][1], xn = xf[it][2];
                float r0 = 1.f / (1.f + expf(-(xr.x + sgh[0][jj][b] + sbias[0][jj])));
                float z0 = 1.f / (1.f + expf(-(xz.x + sgh[1][jj][b] + sbias[1][jj])));
                float n0 = tanhf(xn.x + r0 * (sgh[2][jj][b] + sbias[2][jj]));
                float h0 = (1.f - z0) * n0 + z0 * shp[jj][b];
                float r1 = 1.f / (1.f + expf(-(xr.y + sgh[0][jj + 1][b] + sbias[0][jj + 1])));
                float z1 = 1.f / (1.f + expf(-(xz.y + sgh[1][jj + 1][b] + sbias[1][jj + 1])));
                float n1 = tanhf(xn.y + r1 * (sgh[2][jj + 1][b] + sbias[2][jj + 1]));
                float h1 = (1.f - z1) * n1 + z1 * shp[jj + 1][b];
                shp[jj][b] = h0;
                shp[jj + 1][b] = h1;
                *(float2*)&out[((size_t)te * 32 + b) * 600 + dir * 300 + j0 + jj] =
                    make_float2(h0, h1);
                uint_t u0 = __float_as_uint(h0);
                u0 = (u0 + 0x7fffu + ((u0 >> 16) & 1u)) >> 16;
                uint_t u1 = __float_as_uint(h1);
                u1 = (u1 + 0x7fffu + ((u1 >> 16) & 1u)) >> 16;
                __hip_atomic_store(&dstbuf[b * 156 + ((j0 + jj) >> 1)],
                                   u0 | (u1 << 16), __ATOMIC_RELAXED,
                                   __HIP_MEMORY_SCOPE_AGENT);
            }
        }
        // drain this wave's stores, barrier so ALL waves' stores are down,
        // then publish. No cache-maintenance instructions emitted.
        __builtin_amdgcn_s_waitcnt(0);
        __syncthreads();
        if (tid == 0)
            __hip_atomic_fetch_add(cnt, 1, __ATOMIC_RELAXED,
                                   __HIP_MEMORY_SCOPE_AGENT);
    }
}

// ---------------------------------------------------------------------------
__global__ void span_score(const float* __restrict__ stt,
                           const float* __restrict__ endv,
                           const float* __restrict__ w_a,
                           const int* __restrict__ p_lens,
                           float* __restrict__ final_) {
    int blk = blockIdx.x;          // p*BB + b
    int p = blk / BB, b = blk - p * BB;
    __shared__ float ss[FF];
    __shared__ float wa[FF];
    for (int f = threadIdx.x; f < FF; f += blockDim.x) {
        ss[f] = stt[(size_t)(p * BB + b) * FF + f];
        wa[f] = w_a[f];
    }
    __syncthreads();
    int lane = threadIdx.x & 63, wv = threadIdx.x >> 6;
    int plen = p_lens[b];
    for (int j = wv; j < AA; j += 2) {
        float acc = 0.f;
        int pe = p + j;
        if (pe < PP) {
            const float* ev = endv + (size_t)(pe * BB + b) * FF;
            for (int f = lane; f < FF; f += 64)
                acc += fmaxf(ss[f] + ev[f], 0.f) * wa[f];
        } else {
            for (int f = lane; f < FF; f += 64)
                acc += fmaxf(ss[f], 0.f) * wa[f];
        }
        #pragma unroll
        for (int off = 32; off; off >>= 1) acc += __shfl_down(acc, off);
        if (lane == 0) {
            float v = (pe < plen) ? acc : 0.f;
            final_[(size_t)b * (PP * AA) + p * AA + j] = v;
        }
    }
}

// ---------------------------------------------------------------------------
__global__ void log_softmax_rows(float* __restrict__ out,
                                 const float* __restrict__ final_, int n) {
    int b = blockIdx.x;
    const float* row = final_ + (size_t)b * n;
    __shared__ float red[256];
    float m = -INFINITY;
    for (int i = threadIdx.x; i < n; i += 256) m = fmaxf(m, row[i]);
    red[threadIdx.x] = m;
    __syncthreads();
    for (int s = 128; s; s >>= 1) {
        if (threadIdx.x < s) red[threadIdx.x] = fmaxf(red[threadIdx.x], red[threadIdx.x + s]);
        __syncthreads();
    }
    m = red[0];
    __syncthreads();
    float sum = 0.f;
    for (int i = threadIdx.x; i < n; i += 256) sum += expf(row[i] - m);
    red[threadIdx.x] = sum;
    __syncthreads();
    for (int s = 128; s; s >>= 1) {
        if (threadIdx.x < s) red[threadIdx.x] += red[threadIdx.x + s];
        __syncthreads();
    }
    float lse = m + logf(red[0]);
    for (int i = threadIdx.x; i < n; i += 256) out[(size_t)b * n + i] = row[i] - lse;
}

// ---------------------------------------------------------------------------
extern "C" void kernel_launch(void* const* d_in, const int* in_sizes, int n_in,
                              void* d_out, int out_size, void* d_ws, size_t ws_size,
                              hipStream_t stream) {
    (void)in_sizes; (void)n_in; (void)out_size; (void)ws_size;
    const int*   p_tok  = (const int*)d_in[0];
    const int*   q_tok  = (const int*)d_in[1];
    const float* p_mask = (const float*)d_in[2];
    const float* q_mask = (const float*)d_in[3];
    const int*   p_lens = (const int*)d_in[4];
    const float* embed   = (const float*)d_in[6];
    const float* w_align = (const float*)d_in[7];
    const float* b_align = (const float*)d_in[8];
    const float* w_ih    = (const float*)d_in[9];    // [2,2,900,600]
    const float* w_hh    = (const float*)d_in[10];   // [2,2,900,300]
    const float* b_ih    = (const float*)d_in[11];   // [2,2,900]
    const float* b_hh    = (const float*)d_in[12];   // [2,2,900]
    const float* w_stt   = (const float*)d_in[13];
    const float* b_stt   = (const float*)d_in[14];
    const float* w_end   = (const float*)d_in[15];
    const float* b_end   = (const float*)d_in[16];
    const float* w_a     = (const float*)d_in[17];
    float* out = (float*)d_out;
    float* ws = (float*)d_ws;

    size_t off = 0;
    float* p_emb = ws + off;  off += (size_t)PP * BB * EE;       // 3,840,000
    float* ff_p  = ws + off;  off += (size_t)PP * BB * FF;       // 3,840,000
    float* q_emb = ws + off;  off += (size_t)QQ * BB * EE;       //   288,000
    float* ff_q  = ws + off;  off += (size_t)QQ * BB * FF;       //   288,000
    float* scores= ws + off;  off += (size_t)BB * PP * QQ;       //   384,000
    float* x0    = ws + off;  off += (size_t)PP * BB * 2 * EE;   // 7,680,000
    float* xp_f  = ws + off;  off += (size_t)PP * BB * 900;      // 11,520,000
    float* xp_b  = ws + off;  off += (size_t)PP * BB * 900;      // 11,520,000  (contiguous after xp_f)
    ushort_t* wbf = (ushort_t*)(ws + off); off += 540000;        // 4*900*300 bf16
    uint_t* hbuf = (uint_t*)(ws + off); off += HBUF_DWORDS;      // packed bf16 h
    int*   cnts  = (int*)(ws + off); off += 2 * 2 * 16;          // [L][dir][16]
    float* x1    = p_emb;       // aliases p_emb+ff_p (dead by GRU time)
    float* sttb  = xp_f;        // aliases xp (dead after layer-2 recurrence)
    float* endb  = xp_f + (size_t)PP * BB * FF;
    float* finalb= scores;

    const int M = PP * BB;      // 12800
    const int Mq = QQ * BB;     // 960

    // prep: bf16 recurrent weights + zero h/counters
    convert_whh_bf16<<<(4 * 900 * 300 + 255) / 256, 256, 0, stream>>>(w_hh, wbf);
    init_gru<<<(HBUF_DWORDS + 255) / 256, 256, 0, stream>>>(hbuf, cnts);

    // 1. embedding gathers
    gather_embed<<<(M * EE + 255) / 256, 256, 0, stream>>>(p_tok, embed, p_emb, M);
    gather_embed<<<(Mq * EE + 255) / 256, 256, 0, stream>>>(q_tok, embed, q_emb, Mq);

    // 2. aligned-attention projections (relu)
    gemm_nt_bias<<<dim3((FF + BN - 1) / BN, (M + BM - 1) / BM), 256, 0, stream>>>(
        p_emb, w_align, b_align, ff_p, M, FF, EE, 1);
    gemm_nt_bias<<<dim3((FF + BN - 1) / BN, (Mq + BM - 1) / BM), 256, 0, stream>>>(
        q_emb, w_align, b_align, ff_q, Mq, FF, EE, 1);

    // 3. scores + softmax over q
    scores_softmax<<<PP * BB, 64, 0, stream>>>(ff_p, ff_q, p_mask, q_mask, scores);

    // 4. q_align + concat -> x0 = p_star [P,B,600]
    align_concat<<<PP * BB, 256, 0, stream>>>(scores, q_emb, p_emb, x0);

    // 5. BiGRU, 2 layers: batched xp GEMMs + one persistent MFMA kernel/layer
    for (int l = 0; l < LL; l++) {
        const float* xin = (l == 0) ? x0 : x1;
        float* xout = (l == 0) ? x1 : x0;
        gemm_nt_bias<<<dim3((900 + BN - 1) / BN, (M + BM - 1) / BM), 256, 0, stream>>>(
            xin, w_ih + (size_t)(l * 2 + 0) * 900 * 600, b_ih + (l * 2 + 0) * 900,
            xp_f, M, 900, 600, 0);
        gemm_nt_bias<<<dim3((900 + BN - 1) / BN, (M + BM - 1) / BM), 256, 0, stream>>>(
            xin, w_ih + (size_t)(l * 2 + 1) * 900 * 600, b_ih + (l * 2 + 1) * 900,
            xp_b, M, 900, 600, 0);
        gru_layer<<<2 * GRP, 192, 0, stream>>>(
            xp_f,
            wbf + (size_t)l * 2 * 270000,
            b_hh + (size_t)l * 2 * 900,
            hbuf + (size_t)l * (2 * 2 * 32 * 156),
            cnts + l * 2 * 16,
            xout);
    }

    // 6. stt / end projections (relu) from layer-2 output (in x0)
    gemm_nt_bias<<<dim3((FF + BN - 1) / BN, (M + BM - 1) / BM), 256, 0, stream>>>(
        x0, w_stt, b_stt, sttb, M, FF, 2 * HH, 1);
    gemm_nt_bias<<<dim3((FF + BN - 1) / BN, (M + BM - 1) / BM), 256, 0, stream>>>(
        x0, w_end, b_end, endb, M, FF, 2 * HH, 1);

    // 7. span scores
    span_score<<<PP * BB, 128, 0, stream>>>(sttb, endb, w_a, p_lens, finalb);

    // 8. log-softmax rows -> out
    log_softmax_rows<<<BB, 256, 0, stream>>>(out, finalb, PP * AA);
}

// Round 5
// 6382.476 us; speedup vs baseline: 1.6598x; 1.6598x over previous
//
#include <hip/hip_runtime.h>
#include <hip/hip_bf16.h>
#include <math.h>

// Problem dims
#define PP 400
#define QQ 30
#define BB 32
#define EE 300
#define HH 300
#define FF 300
#define AA 30
#define LL 2

typedef unsigned short ushort_t;
typedef unsigned int uint_t;
typedef __attribute__((ext_vector_type(8))) short short8;
typedef __attribute__((ext_vector_type(16))) float floatx16;
typedef __attribute__((ext_vector_type(4))) uint_t uintx4;

// ---------------------------------------------------------------------------
// Embedding gather: out[row, e] = embed[tok[row], e]
__global__ void gather_embed(const int* __restrict__ tok,
                             const float* __restrict__ embed,
                             float* __restrict__ out, int n_tok) {
    int i = blockIdx.x * blockDim.x + threadIdx.x;
    int n = n_tok * EE;
    if (i >= n) return;
    int row = i / EE, e = i - row * EE;
    out[i] = embed[(size_t)tok[row] * EE + e];
}

// ---------------------------------------------------------------------------
// C[M,N] = A[M,K] @ Bw[N,K]^T + bias[N], optional relu.
#define BM 64
#define BN 64
#define BK 16
__global__ void gemm_nt_bias(const float* __restrict__ A,
                             const float* __restrict__ Bw,
                             const float* __restrict__ bias,
                             float* __restrict__ C,
                             int M, int N, int K, int relu) {
    __shared__ float As[BK][BM];
    __shared__ float Bs[BK][BN];
    int tid = threadIdx.x;
    int row0 = blockIdx.y * BM;
    int col0 = blockIdx.x * BN;
    int tx = tid & 15, ty = tid >> 4;
    int lm = tid >> 2;          // 0..63
    int lk = (tid & 3) * 4;     // 0,4,8,12
    float acc[4][4] = {{0.f}};
    for (int k0 = 0; k0 < K; k0 += BK) {
        float4 av = make_float4(0.f, 0.f, 0.f, 0.f);
        int ar = row0 + lm;
        int kk = k0 + lk;
        if (ar < M) {
            if (kk + 3 < K) {
                av = *(const float4*)(A + (size_t)ar * K + kk);
            } else {
                float t0 = (kk + 0 < K) ? A[(size_t)ar * K + kk + 0] : 0.f;
                float t1 = (kk + 1 < K) ? A[(size_t)ar * K + kk + 1] : 0.f;
                float t2 = (kk + 2 < K) ? A[(size_t)ar * K + kk + 2] : 0.f;
                float t3 = (kk + 3 < K) ? A[(size_t)ar * K + kk + 3] : 0.f;
                av = make_float4(t0, t1, t2, t3);
            }
        }
        As[lk + 0][lm] = av.x; As[lk + 1][lm] = av.y;
        As[lk + 2][lm] = av.z; As[lk + 3][lm] = av.w;

        float4 bv = make_float4(0.f, 0.f, 0.f, 0.f);
        int br = col0 + lm;
        if (br < N) {
            if (kk + 3 < K) {
                bv = *(const float4*)(Bw + (size_t)br * K + kk);
            } else {
                float t0 = (kk + 0 < K) ? Bw[(size_t)br * K + kk + 0] : 0.f;
                float t1 = (kk + 1 < K) ? Bw[(size_t)br * K + kk + 1] : 0.f;
                float t2 = (kk + 2 < K) ? Bw[(size_t)br * K + kk + 2] : 0.f;
                float t3 = (kk + 3 < K) ? Bw[(size_t)br * K + kk + 3] : 0.f;
                bv = make_float4(t0, t1, t2, t3);
            }
        }
        Bs[lk + 0][lm] = bv.x; Bs[lk + 1][lm] = bv.y;
        Bs[lk + 2][lm] = bv.z; Bs[lk + 3][lm] = bv.w;
        __syncthreads();
        #pragma unroll
        for (int k = 0; k < BK; k++) {
            float a[4], b[4];
            #pragma unroll
            for (int i = 0; i < 4; i++) a[i] = As[k][ty * 4 + i];
            #pragma unroll
            for (int j = 0; j < 4; j++) b[j] = Bs[k][tx * 4 + j];
            #pragma unroll
            for (int i = 0; i < 4; i++) {
                #pragma unroll
                for (int j = 0; j < 4; j++) acc[i][j] += a[i] * b[j];
            }
        }
        __syncthreads();
    }
    #pragma unroll
    for (int i = 0; i < 4; i++) {
        int r = row0 + ty * 4 + i;
        if (r >= M) continue;
        #pragma unroll
        for (int j = 0; j < 4; j++) {
            int c = col0 + tx * 4 + j;
            if (c >= N) continue;
            float v = acc[i][j] + bias[c];
            if (relu) v = fmaxf(v, 0.f);
            C[(size_t)r * N + c] = v;
        }
    }
}

// ---------------------------------------------------------------------------
// scores + softmax over q per (p,b)
__global__ void scores_softmax(const float* __restrict__ ffp,
                               const float* __restrict__ ffq,
                               const float* __restrict__ p_mask,
                               const float* __restrict__ q_mask,
                               float* __restrict__ weights) {
    int blk = blockIdx.x;          // p*BB + b
    int p = blk / BB, b = blk - p * BB;
    __shared__ float fp[FF];
    __shared__ float sq[QQ];
    for (int f = threadIdx.x; f < FF; f += blockDim.x)
        fp[f] = ffp[(size_t)(p * BB + b) * FF + f];
    __syncthreads();
    int q = threadIdx.x;
    if (q < QQ) {
        const float* fq = ffq + (size_t)(q * BB + b) * FF;
        float s = 0.f;
        for (int f = 0; f < FF; f++) s += fp[f] * fq[f];
        s *= p_mask[p * BB + b] * q_mask[q * BB + b];
        sq[q] = s;
    }
    __syncthreads();
    if (q < QQ) {
        float m = -INFINITY;
        for (int k = 0; k < QQ; k++) m = fmaxf(m, sq[k]);
        float sum = 0.f;
        for (int k = 0; k < QQ; k++) sum += expf(sq[k] - m);
        weights[(size_t)b * PP * QQ + p * QQ + q] = expf(sq[q] - m) / sum;
    }
}

// ---------------------------------------------------------------------------
__global__ void align_concat(const float* __restrict__ weights,
                             const float* __restrict__ q_emb,
                             const float* __restrict__ p_emb,
                             float* __restrict__ x0) {
    int blk = blockIdx.x;          // p*BB + b
    int p = blk / BB, b = blk - p * BB;
    __shared__ float w[QQ];
    if (threadIdx.x < QQ)
        w[threadIdx.x] = weights[(size_t)b * PP * QQ + p * QQ + threadIdx.x];
    __syncthreads();
    for (int e = threadIdx.x; e < EE; e += blockDim.x) {
        float acc = 0.f;
        for (int q = 0; q < QQ; q++)
            acc += w[q] * q_emb[(size_t)(q * BB + b) * EE + e];
        size_t base = (size_t)(p * BB + b) * (2 * EE);
        x0[base + e] = p_emb[(size_t)(p * BB + b) * EE + e];
        x0[base + EE + e] = acc;
    }
}

// ---------------------------------------------------------------------------
// w_hh fp32 [4][900][300] -> bf16 (RNE) same layout
__global__ void convert_whh_bf16(const float* __restrict__ w,
                                 ushort_t* __restrict__ o) {
    int i = blockIdx.x * blockDim.x + threadIdx.x;
    if (i >= 4 * 900 * 300) return;
    uint_t u = __float_as_uint(w[i]);
    uint_t r = (u + 0x7fffu + ((u >> 16) & 1u)) >> 16;
    o[i] = (ushort_t)r;
}

// zero h double-buffers (both layers, bf16-pair dwords) and group counters
#define HBUF_DWORDS (2 * 2 * 2 * 32 * 156)   // [L][buf][dir][b][156]
__global__ void init_gru(uint_t* __restrict__ hbuf, int* __restrict__ cnt) {
    int i = blockIdx.x * blockDim.x + threadIdx.x;
    if (i < HBUF_DWORDS) hbuf[i] = 0u;
    if (i < 2 * 2 * 16) cnt[i] = 0;
}

// ---------------------------------------------------------------------------
// Persistent BiGRU layer, MFMA recurrence. Grid = 20 blocks x 192 threads:
// group = dir (10 blocks each). Block bi owns j-slice [j0, j0+30) for ALL 32
// batches; per step computes gh[3 gates x 30 j x 32 b] = W_slice @ h via
// v_mfma_f32_32x32x16_bf16, A-fragments resident in VGPRs.
//
// R5 transport fix: h staged from global with ONE asm block of 7 pipelined
// global_load_dwordx4 sc0 sc1 (system-coherent, bypasses stale L1/L2) +
// single s_waitcnt — replaces 26 serialized scalar atomic loads/thread.
// Publish path reordered: h stores -> waitcnt -> barrier -> counter add ->
// out stores (HBM write drain off the critical path).
#define GRP 10
__global__ __launch_bounds__(192, 1) void gru_layer(
        const float* __restrict__ xp_all, // [2 dir][400][32][900] contiguous
        const ushort_t* __restrict__ wbf, // [2 dir][900][300] bf16, this layer
        const float* __restrict__ bhh,    // [2 dir][900], this layer
        uint_t* __restrict__ hbuf,        // [2 buf][2 dir][32][156] dwords
        int* __restrict__ cnts,           // [2 dir][16], this layer
        float* __restrict__ out) {        // [400][32][600]
    int dir = blockIdx.x / GRP;
    int bi  = blockIdx.x - dir * GRP;
    int j0  = bi * 30;
    const float* xp = xp_all + (size_t)dir * (400 * 32 * 900);
    int tid = threadIdx.x;
    int lane = tid & 63;
    int g = tid >> 6;                 // wave id == gate (0=r,1=z,2=n)
    int* cnt = cnts + dir * 16;

    __shared__ __align__(16) ushort_t sh2[32][312]; // h bf16 [batch][k] pad 312
    __shared__ float sgh[3][32][32];  // gh f32 [gate][row][batch]
    __shared__ float shp[30][32];     // private fp32 h [jj][batch]
    __shared__ float sbias[3][32];

    for (int i = tid; i < 30 * 32; i += 192) ((float*)shp)[i] = 0.f;
    if (tid < 96) {
        int gg = tid >> 5, m = tid & 31;
        sbias[gg][m] = (m < 30) ? bhh[dir * 900 + gg * 300 + j0 + m] : 0.f;
    }

    // A-fragments (weights) resident in registers: 19 K-chunks of 16.
    // lane layout for 32x32x16 bf16 A: m = lane&31, k = (lane>>5)*8 + e.
    short8 afrag[19];
    {
        int m = lane & 31, half = lane >> 5;
        const ushort_t* wrow =
            wbf + (size_t)dir * 270000 + (size_t)(g * 300 + j0 + m) * 300;
        for (int c = 0; c < 19; c++) {
            int k0 = c * 16 + half * 8;
            short8 f;
            #pragma unroll
            for (int e = 0; e < 8; e++) {
                int k = k0 + e;
                f[e] = (short)((m < 30 && k < 300) ? wrow[k] : (ushort_t)0);
            }
            afrag[c] = f;
        }
    }
    __syncthreads();

    for (int s = 0; s < PP; s++) {
        int te = dir ? (PP - 1 - s) : s;
        // prefetch xp gate inputs (independent of h; overlaps the poll)
        float2 xf[3][3];
        {
            int it = 0;
            for (int o = tid; o < 480; o += 192, it++) {
                int jp = o >> 5, b = o & 31;
                const float* base =
                    xp + ((size_t)te * 32 + b) * 900 + j0 + jp * 2;
                xf[it][0] = *(const float2*)(base);
                xf[it][1] = *(const float2*)(base + 300);
                xf[it][2] = *(const float2*)(base + 600);
            }
        }
        // wait for previous step's h (relaxed poll, fence-free)
        if (s > 0) {
            if (tid == 0) {
                while (__hip_atomic_load(cnt, __ATOMIC_RELAXED,
                                         __HIP_MEMORY_SCOPE_AGENT) < GRP * s)
                    __builtin_amdgcn_s_sleep(1);
            }
            __syncthreads();
        }
        // stage h: 1248 dwordx4 total; 7 pipelined coherent loads per thread
        {
            const uint_t* src = hbuf + (size_t)(s & 1) * (2 * 32 * 156)
                                + (size_t)dir * (32 * 156);
            int d0 = tid, d1 = tid + 192, d2 = tid + 384, d3 = tid + 576,
                d4 = tid + 768, d5 = tid + 960, d6 = tid + 1152;
            const uint_t* a0 = src + (size_t)d0 * 4;
            const uint_t* a1 = src + (size_t)d1 * 4;
            const uint_t* a2 = src + (size_t)d2 * 4;
            const uint_t* a3 = src + (size_t)d3 * 4;
            const uint_t* a4 = src + (size_t)d4 * 4;
            const uint_t* a5 = src + (size_t)d5 * 4;
            const uint_t* a6 = src + (size_t)((d6 < 1248) ? d6 : 0) * 4;
            uintx4 t0, t1, t2, t3, t4, t5, t6;
            asm volatile(
                "global_load_dwordx4 %0, %7, off sc0 sc1\n\t"
                "global_load_dwordx4 %1, %8, off sc0 sc1\n\t"
                "global_load_dwordx4 %2, %9, off sc0 sc1\n\t"
                "global_load_dwordx4 %3, %10, off sc0 sc1\n\t"
                "global_load_dwordx4 %4, %11, off sc0 sc1\n\t"
                "global_load_dwordx4 %5, %12, off sc0 sc1\n\t"
                "global_load_dwordx4 %6, %13, off sc0 sc1\n\t"
                "s_waitcnt vmcnt(0)"
                : "=&v"(t0), "=&v"(t1), "=&v"(t2), "=&v"(t3),
                  "=&v"(t4), "=&v"(t5), "=&v"(t6)
                : "v"(a0), "v"(a1), "v"(a2), "v"(a3),
                  "v"(a4), "v"(a5), "v"(a6)
                : "memory");
            uint_t* dst = (uint_t*)sh2;
            *(uintx4*)(dst + (size_t)d0 * 4) = t0;
            *(uintx4*)(dst + (size_t)d1 * 4) = t1;
            *(uintx4*)(dst + (size_t)d2 * 4) = t2;
            *(uintx4*)(dst + (size_t)d3 * 4) = t3;
            *(uintx4*)(dst + (size_t)d4 * 4) = t4;
            *(uintx4*)(dst + (size_t)d5 * 4) = t5;
            if (d6 < 1248) *(uintx4*)(dst + (size_t)d6 * 4) = t6;
        }
        __syncthreads();
        // MFMA: this wave's gate tile, A resident, B from LDS
        floatx16 acc;
        #pragma unroll
        for (int r = 0; r < 16; r++) acc[r] = 0.f;
        {
            int n = lane & 31, half = lane >> 5;
            #pragma unroll
            for (int c = 0; c < 19; c++) {
                short8 bf = *(const short8*)&sh2[n][c * 16 + half * 8];
                acc = __builtin_amdgcn_mfma_f32_32x32x16_bf16(
                    afrag[c], bf, acc, 0, 0, 0);
            }
        }
        // C/D layout: col = lane&31, row = (r&3) + 8*(r>>2) + 4*(lane>>5)
        {
            int col = lane & 31, rbase = 4 * (lane >> 5);
            #pragma unroll
            for (int r = 0; r < 16; r++) {
                int row = (r & 3) + 8 * (r >> 2) + rbase;
                sgh[g][row][col] = acc[r];
            }
        }
        __syncthreads();
        // gates + h update; publish h FIRST, out stores after the handoff
        float2 houts[3];
        {
            uint_t* dstbuf = hbuf + (size_t)((s + 1) & 1) * (2 * 32 * 156)
                             + (size_t)dir * (32 * 156);
            int it = 0;
            for (int o = tid; o < 480; o += 192, it++) {
                int jp = o >> 5, b = o & 31;
                int jj = jp * 2;
                float2 xr = xf[it][0], xz = xf[it][1], xn = xf[it][2];
                float r0 = 1.f / (1.f + expf(-(xr.x + sgh[0][jj][b] + sbias[0][jj])));
                float z0 = 1.f / (1.f + expf(-(xz.x + sgh[1][jj][b] + sbias[1][jj])));
                float n0 = tanhf(xn.x + r0 * (sgh[2][jj][b] + sbias[2][jj]));
                float h0 = (1.f - z0) * n0 + z0 * shp[jj][b];
                float r1 = 1.f / (1.f + expf(-(xr.y + sgh[0][jj + 1][b] + sbias[0][jj + 1])));
                float z1 = 1.f / (1.f + expf(-(xz.y + sgh[1][jj + 1][b] + sbias[1][jj + 1])));
                float n1 = tanhf(xn.y + r1 * (sgh[2][jj + 1][b] + sbias[2][jj + 1]));
                float h1 = (1.f - z1) * n1 + z1 * shp[jj + 1][b];
                shp[jj][b] = h0;
                shp[jj + 1][b] = h1;
                houts[it] = make_float2(h0, h1);
                uint_t u0 = __float_as_uint(h0);
                u0 = (u0 + 0x7fffu + ((u0 >> 16) & 1u)) >> 16;
                uint_t u1 = __float_as_uint(h1);
                u1 = (u1 + 0x7fffu + ((u1 >> 16) & 1u)) >> 16;
                __hip_atomic_store(&dstbuf[b * 156 + ((j0 + jj) >> 1)],
                                   u0 | (u1 << 16), __ATOMIC_RELAXED,
                                   __HIP_MEMORY_SCOPE_AGENT);
            }
        }
        // drain h stores, barrier, publish counter — THEN slow out stores
        __builtin_amdgcn_s_waitcnt(0);
        __syncthreads();
        if (tid == 0)
            __hip_atomic_fetch_add(cnt, 1, __ATOMIC_RELAXED,
                                   __HIP_MEMORY_SCOPE_AGENT);
        {
            int it = 0;
            for (int o = tid; o < 480; o += 192, it++) {
                int jp = o >> 5, b = o & 31;
                int jj = jp * 2;
                *(float2*)&out[((size_t)te * 32 + b) * 600 + dir * 300 + j0 + jj] =
                    houts[it];
            }
        }
    }
}

// ---------------------------------------------------------------------------
__global__ void span_score(const float* __restrict__ stt,
                           const float* __restrict__ endv,
                           const float* __restrict__ w_a,
                           const int* __restrict__ p_lens,
                           float* __restrict__ final_) {
    int blk = blockIdx.x;          // p*BB + b
    int p = blk / BB, b = blk - p * BB;
    __shared__ float ss[FF];
    __shared__ float wa[FF];
    for (int f = threadIdx.x; f < FF; f += blockDim.x) {
        ss[f] = stt[(size_t)(p * BB + b) * FF + f];
        wa[f] = w_a[f];
    }
    __syncthreads();
    int lane = threadIdx.x & 63, wv = threadIdx.x >> 6;
    int plen = p_lens[b];
    for (int j = wv; j < AA; j += 2) {
        float acc = 0.f;
        int pe = p + j;
        if (pe < PP) {
            const float* ev = endv + (size_t)(pe * BB + b) * FF;
            for (int f = lane; f < FF; f += 64)
                acc += fmaxf(ss[f] + ev[f], 0.f) * wa[f];
        } else {
            for (int f = lane; f < FF; f += 64)
                acc += fmaxf(ss[f], 0.f) * wa[f];
        }
        #pragma unroll
        for (int off = 32; off; off >>= 1) acc += __shfl_down(acc, off);
        if (lane == 0) {
            float v = (pe < plen) ? acc : 0.f;
            final_[(size_t)b * (PP * AA) + p * AA + j] = v;
        }
    }
}

// ---------------------------------------------------------------------------
__global__ void log_softmax_rows(float* __restrict__ out,
                                 const float* __restrict__ final_, int n) {
    int b = blockIdx.x;
    const float* row = final_ + (size_t)b * n;
    __shared__ float red[256];
    float m = -INFINITY;
    for (int i = threadIdx.x; i < n; i += 256) m = fmaxf(m, row[i]);
    red[threadIdx.x] = m;
    __syncthreads();
    for (int s = 128; s; s >>= 1) {
        if (threadIdx.x < s) red[threadIdx.x] = fmaxf(red[threadIdx.x], red[threadIdx.x + s]);
        __syncthreads();
    }
    m = red[0];
    __syncthreads();
    float sum = 0.f;
    for (int i = threadIdx.x; i < n; i += 256) sum += expf(row[i] - m);
    red[threadIdx.x] = sum;
    __syncthreads();
    for (int s = 128; s; s >>= 1) {
        if (threadIdx.x < s) red[threadIdx.x] += red[threadIdx.x + s];
        __syncthreads();
    }
    float lse = m + logf(red[0]);
    for (int i = threadIdx.x; i < n; i += 256) out[(size_t)b * n + i] = row[i] - lse;
}

// ---------------------------------------------------------------------------
extern "C" void kernel_launch(void* const* d_in, const int* in_sizes, int n_in,
                              void* d_out, int out_size, void* d_ws, size_t ws_size,
                              hipStream_t stream) {
    (void)in_sizes; (void)n_in; (void)out_size; (void)ws_size;
    const int*   p_tok  = (const int*)d_in[0];
    const int*   q_tok  = (const int*)d_in[1];
    const float* p_mask = (const float*)d_in[2];
    const float* q_mask = (const float*)d_in[3];
    const int*   p_lens = (const int*)d_in[4];
    const float* embed   = (const float*)d_in[6];
    const float* w_align = (const float*)d_in[7];
    const float* b_align = (const float*)d_in[8];
    const float* w_ih    = (const float*)d_in[9];    // [2,2,900,600]
    const float* w_hh    = (const float*)d_in[10];   // [2,2,900,300]
    const float* b_ih    = (const float*)d_in[11];   // [2,2,900]
    const float* b_hh    = (const float*)d_in[12];   // [2,2,900]
    const float* w_stt   = (const float*)d_in[13];
    const float* b_stt   = (const float*)d_in[14];
    const float* w_end   = (const float*)d_in[15];
    const float* b_end   = (const float*)d_in[16];
    const float* w_a     = (const float*)d_in[17];
    float* out = (float*)d_out;
    float* ws = (float*)d_ws;

    size_t off = 0;
    float* p_emb = ws + off;  off += (size_t)PP * BB * EE;       // 3,840,000
    float* ff_p  = ws + off;  off += (size_t)PP * BB * FF;       // 3,840,000
    float* q_emb = ws + off;  off += (size_t)QQ * BB * EE;       //   288,000
    float* ff_q  = ws + off;  off += (size_t)QQ * BB * FF;       //   288,000
    float* scores= ws + off;  off += (size_t)BB * PP * QQ;       //   384,000
    float* x0    = ws + off;  off += (size_t)PP * BB * 2 * EE;   // 7,680,000
    float* xp_f  = ws + off;  off += (size_t)PP * BB * 900;      // 11,520,000
    float* xp_b  = ws + off;  off += (size_t)PP * BB * 900;      // 11,520,000  (contiguous after xp_f)
    ushort_t* wbf = (ushort_t*)(ws + off); off += 540000;        // 4*900*300 bf16
    uint_t* hbuf = (uint_t*)(ws + off); off += HBUF_DWORDS;      // packed bf16 h
    int*   cnts  = (int*)(ws + off); off += 2 * 2 * 16;          // [L][dir][16]
    float* x1    = p_emb;       // aliases p_emb+ff_p (dead by GRU time)
    float* sttb  = xp_f;        // aliases xp (dead after layer-2 recurrence)
    float* endb  = xp_f + (size_t)PP * BB * FF;
    float* finalb= scores;

    const int M = PP * BB;      // 12800
    const int Mq = QQ * BB;     // 960

    // prep: bf16 recurrent weights + zero h/counters
    convert_whh_bf16<<<(4 * 900 * 300 + 255) / 256, 256, 0, stream>>>(w_hh, wbf);
    init_gru<<<(HBUF_DWORDS + 255) / 256, 256, 0, stream>>>(hbuf, cnts);

    // 1. embedding gathers
    gather_embed<<<(M * EE + 255) / 256, 256, 0, stream>>>(p_tok, embed, p_emb, M);
    gather_embed<<<(Mq * EE + 255) / 256, 256, 0, stream>>>(q_tok, embed, q_emb, Mq);

    // 2. aligned-attention projections (relu)
    gemm_nt_bias<<<dim3((FF + BN - 1) / BN, (M + BM - 1) / BM), 256, 0, stream>>>(
        p_emb, w_align, b_align, ff_p, M, FF, EE, 1);
    gemm_nt_bias<<<dim3((FF + BN - 1) / BN, (Mq + BM - 1) / BM), 256, 0, stream>>>(
        q_emb, w_align, b_align, ff_q, Mq, FF, EE, 1);

    // 3. scores + softmax over q
    scores_softmax<<<PP * BB, 64, 0, stream>>>(ff_p, ff_q, p_mask, q_mask, scores);

    // 4. q_align + concat -> x0 = p_star [P,B,600]
    align_concat<<<PP * BB, 256, 0, stream>>>(scores, q_emb, p_emb, x0);

    // 5. BiGRU, 2 layers: batched xp GEMMs + one persistent MFMA kernel/layer
    for (int l = 0; l < LL; l++) {
        const float* xin = (l == 0) ? x0 : x1;
        float* xout = (l == 0) ? x1 : x0;
        gemm_nt_bias<<<dim3((900 + BN - 1) / BN, (M + BM - 1) / BM), 256, 0, stream>>>(
            xin, w_ih + (size_t)(l * 2 + 0) * 900 * 600, b_ih + (l * 2 + 0) * 900,
            xp_f, M, 900, 600, 0);
        gemm_nt_bias<<<dim3((900 + BN - 1) / BN, (M + BM - 1) / BM), 256, 0, stream>>>(
            xin, w_ih + (size_t)(l * 2 + 1) * 900 * 600, b_ih + (l * 2 + 1) * 900,
            xp_b, M, 900, 600, 0);
        gru_layer<<<2 * GRP, 192, 0, stream>>>(
            xp_f,
            wbf + (size_t)l * 2 * 270000,
            b_hh + (size_t)l * 2 * 900,
            hbuf + (size_t)l * (2 * 2 * 32 * 156),
            cnts + l * 2 * 16,
            xout);
    }

    // 6. stt / end projections (relu) from layer-2 output (in x0)
    gemm_nt_bias<<<dim3((FF + BN - 1) / BN, (M + BM - 1) / BM), 256, 0, stream>>>(
        x0, w_stt, b_stt, sttb, M, FF, 2 * HH, 1);
    gemm_nt_bias<<<dim3((FF + BN - 1) / BN, (M + BM - 1) / BM), 256, 0, stream>>>(
        x0, w_end, b_end, endb, M, FF, 2 * HH, 1);

    // 7. span scores
    span_score<<<PP * BB, 128, 0, stream>>>(sttb, endb, w_a, p_lens, finalb);

    // 8. log-softmax rows -> out
    log_softmax_rows<<<BB, 256, 0, stream>>>(out, finalb, PP * AA);
}

// Round 6
// 5786.729 us; speedup vs baseline: 1.8307x; 1.1030x over previous
//
#include <hip/hip_runtime.h>
#include <hip/hip_bf16.h>
#include <math.h>

// Problem dims
#define PP 400
#define QQ 30
#define BB 32
#define EE 300
#define HH 300
#define FF 300
#define AA 30
#define LL 2

typedef unsigned short ushort_t;
typedef unsigned int uint_t;
typedef __attribute__((ext_vector_type(8))) short short8;
typedef __attribute__((ext_vector_type(16))) float floatx16;
typedef __attribute__((ext_vector_type(4))) uint_t uintx4;

// ---------------------------------------------------------------------------
// Embedding gather: out[row, e] = embed[tok[row], e]
__global__ void gather_embed(const int* __restrict__ tok,
                             const float* __restrict__ embed,
                             float* __restrict__ out, int n_tok) {
    int i = blockIdx.x * blockDim.x + threadIdx.x;
    int n = n_tok * EE;
    if (i >= n) return;
    int row = i / EE, e = i - row * EE;
    out[i] = embed[(size_t)tok[row] * EE + e];
}

// ---------------------------------------------------------------------------
// C[M,N] = A[M,K] @ Bw[N,K]^T + bias[N], optional relu.
#define BM 64
#define BN 64
#define BK 16
__global__ void gemm_nt_bias(const float* __restrict__ A,
                             const float* __restrict__ Bw,
                             const float* __restrict__ bias,
                             float* __restrict__ C,
                             int M, int N, int K, int relu) {
    __shared__ float As[BK][BM];
    __shared__ float Bs[BK][BN];
    int tid = threadIdx.x;
    int row0 = blockIdx.y * BM;
    int col0 = blockIdx.x * BN;
    int tx = tid & 15, ty = tid >> 4;
    int lm = tid >> 2;          // 0..63
    int lk = (tid & 3) * 4;     // 0,4,8,12
    float acc[4][4] = {{0.f}};
    for (int k0 = 0; k0 < K; k0 += BK) {
        float4 av = make_float4(0.f, 0.f, 0.f, 0.f);
        int ar = row0 + lm;
        int kk = k0 + lk;
        if (ar < M) {
            if (kk + 3 < K) {
                av = *(const float4*)(A + (size_t)ar * K + kk);
            } else {
                float t0 = (kk + 0 < K) ? A[(size_t)ar * K + kk + 0] : 0.f;
                float t1 = (kk + 1 < K) ? A[(size_t)ar * K + kk + 1] : 0.f;
                float t2 = (kk + 2 < K) ? A[(size_t)ar * K + kk + 2] : 0.f;
                float t3 = (kk + 3 < K) ? A[(size_t)ar * K + kk + 3] : 0.f;
                av = make_float4(t0, t1, t2, t3);
            }
        }
        As[lk + 0][lm] = av.x; As[lk + 1][lm] = av.y;
        As[lk + 2][lm] = av.z; As[lk + 3][lm] = av.w;

        float4 bv = make_float4(0.f, 0.f, 0.f, 0.f);
        int br = col0 + lm;
        if (br < N) {
            if (kk + 3 < K) {
                bv = *(const float4*)(Bw + (size_t)br * K + kk);
            } else {
                float t0 = (kk + 0 < K) ? Bw[(size_t)br * K + kk + 0] : 0.f;
                float t1 = (kk + 1 < K) ? Bw[(size_t)br * K + kk + 1] : 0.f;
                float t2 = (kk + 2 < K) ? Bw[(size_t)br * K + kk + 2] : 0.f;
                float t3 = (kk + 3 < K) ? Bw[(size_t)br * K + kk + 3] : 0.f;
                bv = make_float4(t0, t1, t2, t3);
            }
        }
        Bs[lk + 0][lm] = bv.x; Bs[lk + 1][lm] = bv.y;
        Bs[lk + 2][lm] = bv.z; Bs[lk + 3][lm] = bv.w;
        __syncthreads();
        #pragma unroll
        for (int k = 0; k < BK; k++) {
            float a[4], b[4];
            #pragma unroll
            for (int i = 0; i < 4; i++) a[i] = As[k][ty * 4 + i];
            #pragma unroll
            for (int j = 0; j < 4; j++) b[j] = Bs[k][tx * 4 + j];
            #pragma unroll
            for (int i = 0; i < 4; i++) {
                #pragma unroll
                for (int j = 0; j < 4; j++) acc[i][j] += a[i] * b[j];
            }
        }
        __syncthreads();
    }
    #pragma unroll
    for (int i = 0; i < 4; i++) {
        int r = row0 + ty * 4 + i;
        if (r >= M) continue;
        #pragma unroll
        for (int j = 0; j < 4; j++) {
            int c = col0 + tx * 4 + j;
            if (c >= N) continue;
            float v = acc[i][j] + bias[c];
            if (relu) v = fmaxf(v, 0.f);
            C[(size_t)r * N + c] = v;
        }
    }
}

// ---------------------------------------------------------------------------
// scores + softmax over q per (p,b)
__global__ void scores_softmax(const float* __restrict__ ffp,
                               const float* __restrict__ ffq,
                               const float* __restrict__ p_mask,
                               const float* __restrict__ q_mask,
                               float* __restrict__ weights) {
    int blk = blockIdx.x;          // p*BB + b
    int p = blk / BB, b = blk - p * BB;
    __shared__ float fp[FF];
    __shared__ float sq[QQ];
    for (int f = threadIdx.x; f < FF; f += blockDim.x)
        fp[f] = ffp[(size_t)(p * BB + b) * FF + f];
    __syncthreads();
    int q = threadIdx.x;
    if (q < QQ) {
        const float* fq = ffq + (size_t)(q * BB + b) * FF;
        float s = 0.f;
        for (int f = 0; f < FF; f++) s += fp[f] * fq[f];
        s *= p_mask[p * BB + b] * q_mask[q * BB + b];
        sq[q] = s;
    }
    __syncthreads();
    if (q < QQ) {
        float m = -INFINITY;
        for (int k = 0; k < QQ; k++) m = fmaxf(m, sq[k]);
        float sum = 0.f;
        for (int k = 0; k < QQ; k++) sum += expf(sq[k] - m);
        weights[(size_t)b * PP * QQ + p * QQ + q] = expf(sq[q] - m) / sum;
    }
}

// ---------------------------------------------------------------------------
__global__ void align_concat(const float* __restrict__ weights,
                             const float* __restrict__ q_emb,
                             const float* __restrict__ p_emb,
                             float* __restrict__ x0) {
    int blk = blockIdx.x;          // p*BB + b
    int p = blk / BB, b = blk - p * BB;
    __shared__ float w[QQ];
    if (threadIdx.x < QQ)
        w[threadIdx.x] = weights[(size_t)b * PP * QQ + p * QQ + threadIdx.x];
    __syncthreads();
    for (int e = threadIdx.x; e < EE; e += blockDim.x) {
        float acc = 0.f;
        for (int q = 0; q < QQ; q++)
            acc += w[q] * q_emb[(size_t)(q * BB + b) * EE + e];
        size_t base = (size_t)(p * BB + b) * (2 * EE);
        x0[base + e] = p_emb[(size_t)(p * BB + b) * EE + e];
        x0[base + EE + e] = acc;
    }
}

// ---------------------------------------------------------------------------
// w_hh fp32 [4][900][300] -> bf16 (RNE) same layout
__global__ void convert_whh_bf16(const float* __restrict__ w,
                                 ushort_t* __restrict__ o) {
    int i = blockIdx.x * blockDim.x + threadIdx.x;
    if (i >= 4 * 900 * 300) return;
    uint_t u = __float_as_uint(w[i]);
    uint_t r = (u + 0x7fffu + ((u >> 16) & 1u)) >> 16;
    o[i] = (ushort_t)r;
}

// ---------------------------------------------------------------------------
// Persistent BiGRU layer, MFMA recurrence, TAGGED-PACKET handoff.
// Grid = 20 blocks x 192 threads: dir-group of 10 blocks; block bi owns
// j-slice [j0, j0+30) for all 32 batches. Per step each wave (=gate) does
// v_mfma_f32_32x32x16_bf16 with its weight A-fragments RESIDENT in VGPRs.
//
// Handoff (R6): h is exchanged as 16B packets {3 dwords = 6 bf16 h, 1 dword
// tag}. A dwordx4 sc0 sc1 store is a single LLC transaction, so a matching
// tag certifies the h data delivered in the SAME load — no producer drain,
// no counter, no separate fetch. 8-slot ring (inter-block lag is <= 1 step
// by the all-to-all dependence, so no overwrite hazard). Tags are unique
// per (layer, step); 0xAA poison never matches.
#define GRP 10
#define RSLOT 8
// hbuf layout (dwords): [dir][slot][packet 0..1599][4];  packet =
// (bi*32 + b)*5 + q,  q-th packet of (bi,b) holds h[j0+6q .. j0+6q+5].
#define HBUF_DWORDS (2 * RSLOT * 1600 * 4)

__global__ __launch_bounds__(192, 1) void gru_layer(
        const float* __restrict__ xp_all, // [2 dir][400][32][900] contiguous
        const ushort_t* __restrict__ wbf, // [2 dir][900][300] bf16, this layer
        const float* __restrict__ bhh,    // [2 dir][900], this layer
        uint_t* __restrict__ hbuf,        // shared packet ring
        int layer,
        float* __restrict__ out) {        // [400][32][600]
    int dir = blockIdx.x / GRP;
    int bi  = blockIdx.x - dir * GRP;
    int j0  = bi * 30;
    const float* xp = xp_all + (size_t)dir * (400 * 32 * 900);
    int tid = threadIdx.x;
    int lane = tid & 63;
    int g = tid >> 6;                 // wave id == gate (0=r,1=z,2=n)
    uint_t* hb_dir = hbuf + (size_t)dir * (RSLOT * 6400);

    __shared__ __align__(16) ushort_t sh2[32][312]; // h bf16 [batch][k]
    __shared__ float sgh[3][32][32];  // gh f32 [gate][row][batch]
    __shared__ float shp[30][32];     // private fp32 h [jj][batch]
    __shared__ float sbias[3][32];
    __shared__ uint_t spub[32][17];   // packed h pairs [b][jp], stride 17

    for (int i = tid; i < 30 * 32; i += 192) ((float*)shp)[i] = 0.f;
    for (int i = tid; i < 32 * 156; i += 192) ((uint_t*)sh2)[i] = 0u;
    if (tid < 96) {
        int gg = tid >> 5, m = tid & 31;
        sbias[gg][m] = (m < 30) ? bhh[dir * 900 + gg * 300 + j0 + m] : 0.f;
    }

    // A-fragments (weights) resident in registers: 19 K-chunks of 16.
    // lane layout for 32x32x16 bf16 A: m = lane&31, k = (lane>>5)*8 + e.
    short8 afrag[19];
    {
        int m = lane & 31, half = lane >> 5;
        const ushort_t* wrow =
            wbf + (size_t)dir * 270000 + (size_t)(g * 300 + j0 + m) * 300;
        for (int c = 0; c < 19; c++) {
            int k0 = c * 16 + half * 8;
            short8 f;
            #pragma unroll
            for (int e = 0; e < 8; e++) {
                int k = k0 + e;
                f[e] = (short)((m < 30 && k < 300) ? wrow[k] : (ushort_t)0);
            }
            afrag[c] = f;
        }
    }
    // per-thread fixed packet assignments (9 each, wrap duplicates benign)
    int Pk[9], dstoff[9];
    #pragma unroll
    for (int k = 0; k < 9; k++) {
        int P = tid + 192 * k;
        if (P >= 1600) P -= 1600;
        Pk[k] = P;
        int pbi = P / 160, rem = P - pbi * 160;
        int pb = rem / 5, pq = rem - pb * 5;
        dstoff[k] = pb * 156 + pbi * 15 + 3 * pq;
    }
    __syncthreads();

    for (int s = 0; s < PP; s++) {
        int te = dir ? (PP - 1 - s) : s;
        // prefetch xp gate inputs (independent of h; overlaps the poll)
        float2 xf[3][3];
        {
            int it = 0;
            for (int o = tid; o < 480; o += 192, it++) {
                int jp = o >> 5, b = o & 31;
                const float* base =
                    xp + ((size_t)te * 32 + b) * 900 + j0 + jp * 2;
                xf[it][0] = *(const float2*)(base);
                xf[it][1] = *(const float2*)(base + 300);
                xf[it][2] = *(const float2*)(base + 600);
            }
        }
        // poll tagged packets for h(s); unpack straight into sh2
        if (s > 0) {
            uint_t want = (uint_t)(layer * 1024 + s);
            const uint_t* base = hb_dir + (size_t)(s & 7) * 6400;
            uintx4 val[9];
            int pend = 0x1FF;
            uint_t* shdw = (uint_t*)sh2;
            while (pend) {
                #pragma unroll
                for (int k = 0; k < 9; k++) {
                    if (pend & (1 << k)) {
                        const uint_t* a = base + (size_t)Pk[k] * 4;
                        asm volatile(
                            "global_load_dwordx4 %0, %1, off sc0 sc1"
                            : "=&v"(val[k]) : "v"(a) : "memory");
                    }
                }
                asm volatile("s_waitcnt vmcnt(0)" ::: "memory");
                #pragma unroll
                for (int k = 0; k < 9; k++) {
                    if ((pend & (1 << k)) && val[k].w == want) {
                        pend &= ~(1 << k);
                        shdw[dstoff[k] + 0] = val[k].x;
                        shdw[dstoff[k] + 1] = val[k].y;
                        shdw[dstoff[k] + 2] = val[k].z;
                    }
                }
                if (pend) __builtin_amdgcn_s_sleep(1);
            }
        }
        __syncthreads();
        // MFMA: this wave's gate tile, A resident, B from LDS
        floatx16 acc;
        #pragma unroll
        for (int r = 0; r < 16; r++) acc[r] = 0.f;
        {
            int n = lane & 31, half = lane >> 5;
            #pragma unroll
            for (int c = 0; c < 19; c++) {
                short8 bf = *(const short8*)&sh2[n][c * 16 + half * 8];
                acc = __builtin_amdgcn_mfma_f32_32x32x16_bf16(
                    afrag[c], bf, acc, 0, 0, 0);
            }
        }
        // C/D layout: col = lane&31, row = (r&3) + 8*(r>>2) + 4*(lane>>5)
        {
            int col = lane & 31, rbase = 4 * (lane >> 5);
            #pragma unroll
            for (int r = 0; r < 16; r++) {
                int row = (r & 3) + 8 * (r >> 2) + rbase;
                sgh[g][row][col] = acc[r];
            }
        }
        __syncthreads();
        // gates + h update; stash packed pairs in LDS for the publishers
        float2 houts[3];
        {
            int it = 0;
            for (int o = tid; o < 480; o += 192, it++) {
                int jp = o >> 5, b = o & 31;
                int jj = jp * 2;
                float2 xr = xf[it][0], xz = xf[it][1], xn = xf[it][2];
                float r0 = 1.f / (1.f + expf(-(xr.x + sgh[0][jj][b] + sbias[0][jj])));
                float z0 = 1.f / (1.f + expf(-(xz.x + sgh[1][jj][b] + sbias[1][jj])));
                float n0 = tanhf(xn.x + r0 * (sgh[2][jj][b] + sbias[2][jj]));
                float h0 = (1.f - z0) * n0 + z0 * shp[jj][b];
                float r1 = 1.f / (1.f + expf(-(xr.y + sgh[0][jj + 1][b] + sbias[0][jj + 1])));
                float z1 = 1.f / (1.f + expf(-(xz.y + sgh[1][jj + 1][b] + sbias[1][jj + 1])));
                float n1 = tanhf(xn.y + r1 * (sgh[2][jj + 1][b] + sbias[2][jj + 1]));
                float h1 = (1.f - z1) * n1 + z1 * shp[jj + 1][b];
                shp[jj][b] = h0;
                shp[jj + 1][b] = h1;
                houts[it] = make_float2(h0, h1);
                uint_t u0 = __float_as_uint(h0);
                u0 = (u0 + 0x7fffu + ((u0 >> 16) & 1u)) >> 16;
                uint_t u1 = __float_as_uint(h1);
                u1 = (u1 + 0x7fffu + ((u1 >> 16) & 1u)) >> 16;
                spub[b][jp] = u0 | (u1 << 16);
            }
        }
        __syncthreads();
        // publishers: 160 threads, one 16B tagged packet each, fire&forget
        if (tid < 160) {
            int pb = tid / 5, pq = tid - pb * 5;
            uintx4 pkt;
            pkt.x = spub[pb][3 * pq + 0];
            pkt.y = spub[pb][3 * pq + 1];
            pkt.z = spub[pb][3 * pq + 2];
            pkt.w = (uint_t)(layer * 1024 + s + 1);
            uint_t* pa = hb_dir + (size_t)((s + 1) & 7) * 6400
                         + (size_t)(((bi * 32) + pb) * 5 + pq) * 4;
            asm volatile("global_store_dwordx4 %0, %1, off sc0 sc1"
                         :: "v"(pa), "v"(pkt) : "memory");
        }
        // out stores (fire & forget, off the handoff critical path)
        {
            int it = 0;
            for (int o = tid; o < 480; o += 192, it++) {
                int jp = o >> 5, b = o & 31;
                int jj = jp * 2;
                *(float2*)&out[((size_t)te * 32 + b) * 600 + dir * 300 + j0 + jj] =
                    houts[it];
            }
        }
    }
}

// ---------------------------------------------------------------------------
__global__ void span_score(const float* __restrict__ stt,
                           const float* __restrict__ endv,
                           const float* __restrict__ w_a,
                           const int* __restrict__ p_lens,
                           float* __restrict__ final_) {
    int blk = blockIdx.x;          // p*BB + b
    int p = blk / BB, b = blk - p * BB;
    __shared__ float ss[FF];
    __shared__ float wa[FF];
    for (int f = threadIdx.x; f < FF; f += blockDim.x) {
        ss[f] = stt[(size_t)(p * BB + b) * FF + f];
        wa[f] = w_a[f];
    }
    __syncthreads();
    int lane = threadIdx.x & 63, wv = threadIdx.x >> 6;
    int plen = p_lens[b];
    for (int j = wv; j < AA; j += 2) {
        float acc = 0.f;
        int pe = p + j;
        if (pe < PP) {
            const float* ev = endv + (size_t)(pe * BB + b) * FF;
            for (int f = lane; f < FF; f += 64)
                acc += fmaxf(ss[f] + ev[f], 0.f) * wa[f];
        } else {
            for (int f = lane; f < FF; f += 64)
                acc += fmaxf(ss[f], 0.f) * wa[f];
        }
        #pragma unroll
        for (int off = 32; off; off >>= 1) acc += __shfl_down(acc, off);
        if (lane == 0) {
            float v = (pe < plen) ? acc : 0.f;
            final_[(size_t)b * (PP * AA) + p * AA + j] = v;
        }
    }
}

// ---------------------------------------------------------------------------
__global__ void log_softmax_rows(float* __restrict__ out,
                                 const float* __restrict__ final_, int n) {
    int b = blockIdx.x;
    const float* row = final_ + (size_t)b * n;
    __shared__ float red[256];
    float m = -INFINITY;
    for (int i = threadIdx.x; i < n; i += 256) m = fmaxf(m, row[i]);
    red[threadIdx.x] = m;
    __syncthreads();
    for (int s = 128; s; s >>= 1) {
        if (threadIdx.x < s) red[threadIdx.x] = fmaxf(red[threadIdx.x], red[threadIdx.x + s]);
        __syncthreads();
    }
    m = red[0];
    __syncthreads();
    float sum = 0.f;
    for (int i = threadIdx.x; i < n; i += 256) sum += expf(row[i] - m);
    red[threadIdx.x] = sum;
    __syncthreads();
    for (int s = 128; s; s >>= 1) {
        if (threadIdx.x < s) red[threadIdx.x] += red[threadIdx.x + s];
        __syncthreads();
    }
    float lse = m + logf(red[0]);
    for (int i = threadIdx.x; i < n; i += 256) out[(size_t)b * n + i] = row[i] - lse;
}

// ---------------------------------------------------------------------------
extern "C" void kernel_launch(void* const* d_in, const int* in_sizes, int n_in,
                              void* d_out, int out_size, void* d_ws, size_t ws_size,
                              hipStream_t stream) {
    (void)in_sizes; (void)n_in; (void)out_size; (void)ws_size;
    const int*   p_tok  = (const int*)d_in[0];
    const int*   q_tok  = (const int*)d_in[1];
    const float* p_mask = (const float*)d_in[2];
    const float* q_mask = (const float*)d_in[3];
    const int*   p_lens = (const int*)d_in[4];
    const float* embed   = (const float*)d_in[6];
    const float* w_align = (const float*)d_in[7];
    const float* b_align = (const float*)d_in[8];
    const float* w_ih    = (const float*)d_in[9];    // [2,2,900,600]
    const float* w_hh    = (const float*)d_in[10];   // [2,2,900,300]
    const float* b_ih    = (const float*)d_in[11];   // [2,2,900]
    const float* b_hh    = (const float*)d_in[12];   // [2,2,900]
    const float* w_stt   = (const float*)d_in[13];
    const float* b_stt   = (const float*)d_in[14];
    const float* w_end   = (const float*)d_in[15];
    const float* b_end   = (const float*)d_in[16];
    const float* w_a     = (const float*)d_in[17];
    float* out = (float*)d_out;
    float* ws = (float*)d_ws;

    size_t off = 0;
    float* p_emb = ws + off;  off += (size_t)PP * BB * EE;       // 3,840,000
    float* ff_p  = ws + off;  off += (size_t)PP * BB * FF;       // 3,840,000
    float* q_emb = ws + off;  off += (size_t)QQ * BB * EE;       //   288,000
    float* ff_q  = ws + off;  off += (size_t)QQ * BB * FF;       //   288,000
    float* scores= ws + off;  off += (size_t)BB * PP * QQ;       //   384,000
    float* x0    = ws + off;  off += (size_t)PP * BB * 2 * EE;   // 7,680,000
    float* xp_f  = ws + off;  off += (size_t)PP * BB * 900;      // 11,520,000
    float* xp_b  = ws + off;  off += (size_t)PP * BB * 900;      // 11,520,000  (contiguous after xp_f)
    ushort_t* wbf = (ushort_t*)(ws + off); off += 540000;        // 4*900*300 bf16
    uint_t* hbuf = (uint_t*)(ws + off); off += HBUF_DWORDS;      // packet ring
    float* x1    = p_emb;       // aliases p_emb+ff_p (dead by GRU time)
    float* sttb  = xp_f;        // aliases xp (dead after layer-2 recurrence)
    float* endb  = xp_f + (size_t)PP * BB * FF;
    float* finalb= scores;

    const int M = PP * BB;      // 12800
    const int Mq = QQ * BB;     // 960

    // prep: bf16 recurrent weights (packet ring needs NO init: 0xAA poison
    // and cross-layer tags can never equal a live tag)
    convert_whh_bf16<<<(4 * 900 * 300 + 255) / 256, 256, 0, stream>>>(w_hh, wbf);

    // 1. embedding gathers
    gather_embed<<<(M * EE + 255) / 256, 256, 0, stream>>>(p_tok, embed, p_emb, M);
    gather_embed<<<(Mq * EE + 255) / 256, 256, 0, stream>>>(q_tok, embed, q_emb, Mq);

    // 2. aligned-attention projections (relu)
    gemm_nt_bias<<<dim3((FF + BN - 1) / BN, (M + BM - 1) / BM), 256, 0, stream>>>(
        p_emb, w_align, b_align, ff_p, M, FF, EE, 1);
    gemm_nt_bias<<<dim3((FF + BN - 1) / BN, (Mq + BM - 1) / BM), 256, 0, stream>>>(
        q_emb, w_align, b_align, ff_q, Mq, FF, EE, 1);

    // 3. scores + softmax over q
    scores_softmax<<<PP * BB, 64, 0, stream>>>(ff_p, ff_q, p_mask, q_mask, scores);

    // 4. q_align + concat -> x0 = p_star [P,B,600]
    align_concat<<<PP * BB, 256, 0, stream>>>(scores, q_emb, p_emb, x0);

    // 5. BiGRU, 2 layers: batched xp GEMMs + one persistent MFMA kernel/layer
    for (int l = 0; l < LL; l++) {
        const float* xin = (l == 0) ? x0 : x1;
        float* xout = (l == 0) ? x1 : x0;
        gemm_nt_bias<<<dim3((900 + BN - 1) / BN, (M + BM - 1) / BM), 256, 0, stream>>>(
            xin, w_ih + (size_t)(l * 2 + 0) * 900 * 600, b_ih + (l * 2 + 0) * 900,
            xp_f, M, 900, 600, 0);
        gemm_nt_bias<<<dim3((900 + BN - 1) / BN, (M + BM - 1) / BM), 256, 0, stream>>>(
            xin, w_ih + (size_t)(l * 2 + 1) * 900 * 600, b_ih + (l * 2 + 1) * 900,
            xp_b, M, 900, 600, 0);
        gru_layer<<<2 * GRP, 192, 0, stream>>>(
            xp_f,
            wbf + (size_t)l * 2 * 270000,
            b_hh + (size_t)l * 2 * 900,
            hbuf, l, xout);
    }

    // 6. stt / end projections (relu) from layer-2 output (in x0)
    gemm_nt_bias<<<dim3((FF + BN - 1) / BN, (M + BM - 1) / BM), 256, 0, stream>>>(
        x0, w_stt, b_stt, sttb, M, FF, 2 * HH, 1);
    gemm_nt_bias<<<dim3((FF + BN - 1) / BN, (M + BM - 1) / BM), 256, 0, stream>>>(
        x0, w_end, b_end, endb, M, FF, 2 * HH, 1);

    // 7. span scores
    span_score<<<PP * BB, 128, 0, stream>>>(sttb, endb, w_a, p_lens, finalb);

    // 8. log-softmax rows -> out
    log_softmax_rows<<<BB, 256, 0, stream>>>(out, finalb, PP * AA);
}

// Round 7
// 4723.885 us; speedup vs baseline: 2.2425x; 1.2250x over previous
//
#include <hip/hip_runtime.h>
#include <hip/hip_bf16.h>
#include <math.h>

// Problem dims
#define PP 400
#define QQ 30
#define BB 32
#define EE 300
#define HH 300
#define FF 300
#define AA 30
#define LL 2

typedef unsigned short ushort_t;
typedef unsigned int uint_t;
typedef __attribute__((ext_vector_type(8))) short short8;
typedef __attribute__((ext_vector_type(16))) float floatx16;
typedef __attribute__((ext_vector_type(4))) uint_t uintx4;

// ---------------------------------------------------------------------------
// Embedding gather: out[row, e] = embed[tok[row], e]
__global__ void gather_embed(const int* __restrict__ tok,
                             const float* __restrict__ embed,
                             float* __restrict__ out, int n_tok) {
    int i = blockIdx.x * blockDim.x + threadIdx.x;
    int n = n_tok * EE;
    if (i >= n) return;
    int row = i / EE, e = i - row * EE;
    out[i] = embed[(size_t)tok[row] * EE + e];
}

// ---------------------------------------------------------------------------
// C[M,N] = A[M,K] @ Bw[N,K]^T + bias[N], optional relu.
#define BM 64
#define BN 64
#define BK 16
__global__ void gemm_nt_bias(const float* __restrict__ A,
                             const float* __restrict__ Bw,
                             const float* __restrict__ bias,
                             float* __restrict__ C,
                             int M, int N, int K, int relu) {
    __shared__ float As[BK][BM];
    __shared__ float Bs[BK][BN];
    int tid = threadIdx.x;
    int row0 = blockIdx.y * BM;
    int col0 = blockIdx.x * BN;
    int tx = tid & 15, ty = tid >> 4;
    int lm = tid >> 2;          // 0..63
    int lk = (tid & 3) * 4;     // 0,4,8,12
    float acc[4][4] = {{0.f}};
    for (int k0 = 0; k0 < K; k0 += BK) {
        float4 av = make_float4(0.f, 0.f, 0.f, 0.f);
        int ar = row0 + lm;
        int kk = k0 + lk;
        if (ar < M) {
            if (kk + 3 < K) {
                av = *(const float4*)(A + (size_t)ar * K + kk);
            } else {
                float t0 = (kk + 0 < K) ? A[(size_t)ar * K + kk + 0] : 0.f;
                float t1 = (kk + 1 < K) ? A[(size_t)ar * K + kk + 1] : 0.f;
                float t2 = (kk + 2 < K) ? A[(size_t)ar * K + kk + 2] : 0.f;
                float t3 = (kk + 3 < K) ? A[(size_t)ar * K + kk + 3] : 0.f;
                av = make_float4(t0, t1, t2, t3);
            }
        }
        As[lk + 0][lm] = av.x; As[lk + 1][lm] = av.y;
        As[lk + 2][lm] = av.z; As[lk + 3][lm] = av.w;

        float4 bv = make_float4(0.f, 0.f, 0.f, 0.f);
        int br = col0 + lm;
        if (br < N) {
            if (kk + 3 < K) {
                bv = *(const float4*)(Bw + (size_t)br * K + kk);
            } else {
                float t0 = (kk + 0 < K) ? Bw[(size_t)br * K + kk + 0] : 0.f;
                float t1 = (kk + 1 < K) ? Bw[(size_t)br * K + kk + 1] : 0.f;
                float t2 = (kk + 2 < K) ? Bw[(size_t)br * K + kk + 2] : 0.f;
                float t3 = (kk + 3 < K) ? Bw[(size_t)br * K + kk + 3] : 0.f;
                bv = make_float4(t0, t1, t2, t3);
            }
        }
        Bs[lk + 0][lm] = bv.x; Bs[lk + 1][lm] = bv.y;
        Bs[lk + 2][lm] = bv.z; Bs[lk + 3][lm] = bv.w;
        __syncthreads();
        #pragma unroll
        for (int k = 0; k < BK; k++) {
            float a[4], b[4];
            #pragma unroll
            for (int i = 0; i < 4; i++) a[i] = As[k][ty * 4 + i];
            #pragma unroll
            for (int j = 0; j < 4; j++) b[j] = Bs[k][tx * 4 + j];
            #pragma unroll
            for (int i = 0; i < 4; i++) {
                #pragma unroll
                for (int j = 0; j < 4; j++) acc[i][j] += a[i] * b[j];
            }
        }
        __syncthreads();
    }
    #pragma unroll
    for (int i = 0; i < 4; i++) {
        int r = row0 + ty * 4 + i;
        if (r >= M) continue;
        #pragma unroll
        for (int j = 0; j < 4; j++) {
            int c = col0 + tx * 4 + j;
            if (c >= N) continue;
            float v = acc[i][j] + bias[c];
            if (relu) v = fmaxf(v, 0.f);
            C[(size_t)r * N + c] = v;
        }
    }
}

// ---------------------------------------------------------------------------
// scores + softmax over q per (p,b)
__global__ void scores_softmax(const float* __restrict__ ffp,
                               const float* __restrict__ ffq,
                               const float* __restrict__ p_mask,
                               const float* __restrict__ q_mask,
                               float* __restrict__ weights) {
    int blk = blockIdx.x;          // p*BB + b
    int p = blk / BB, b = blk - p * BB;
    __shared__ float fp[FF];
    __shared__ float sq[QQ];
    for (int f = threadIdx.x; f < FF; f += blockDim.x)
        fp[f] = ffp[(size_t)(p * BB + b) * FF + f];
    __syncthreads();
    int q = threadIdx.x;
    if (q < QQ) {
        const float* fq = ffq + (size_t)(q * BB + b) * FF;
        float s = 0.f;
        for (int f = 0; f < FF; f++) s += fp[f] * fq[f];
        s *= p_mask[p * BB + b] * q_mask[q * BB + b];
        sq[q] = s;
    }
    __syncthreads();
    if (q < QQ) {
        float m = -INFINITY;
        for (int k = 0; k < QQ; k++) m = fmaxf(m, sq[k]);
        float sum = 0.f;
        for (int k = 0; k < QQ; k++) sum += expf(sq[k] - m);
        weights[(size_t)b * PP * QQ + p * QQ + q] = expf(sq[q] - m) / sum;
    }
}

// ---------------------------------------------------------------------------
__global__ void align_concat(const float* __restrict__ weights,
                             const float* __restrict__ q_emb,
                             const float* __restrict__ p_emb,
                             float* __restrict__ x0) {
    int blk = blockIdx.x;          // p*BB + b
    int p = blk / BB, b = blk - p * BB;
    __shared__ float w[QQ];
    if (threadIdx.x < QQ)
        w[threadIdx.x] = weights[(size_t)b * PP * QQ + p * QQ + threadIdx.x];
    __syncthreads();
    for (int e = threadIdx.x; e < EE; e += blockDim.x) {
        float acc = 0.f;
        for (int q = 0; q < QQ; q++)
            acc += w[q] * q_emb[(size_t)(q * BB + b) * EE + e];
        size_t base = (size_t)(p * BB + b) * (2 * EE);
        x0[base + e] = p_emb[(size_t)(p * BB + b) * EE + e];
        x0[base + EE + e] = acc;
    }
}

// ---------------------------------------------------------------------------
// w_hh fp32 [4][900][300] -> bf16 (RNE) same layout
__global__ void convert_whh_bf16(const float* __restrict__ w,
                                 ushort_t* __restrict__ o) {
    int i = blockIdx.x * blockDim.x + threadIdx.x;
    if (i >= 4 * 900 * 300) return;
    uint_t u = __float_as_uint(w[i]);
    uint_t r = (u + 0x7fffu + ((u >> 16) & 1u)) >> 16;
    o[i] = (ushort_t)r;
}

// ---------------------------------------------------------------------------
// Persistent BiGRU layer, MFMA recurrence, TAGGED-PACKET handoff (R7).
// Grid = 10 blocks x 512 threads: 5 blocks per dir; block bi owns j-slice
// [j0, j0+60) for all 32 batches. Waves 0-5 each hold one 32-row M-tile of
// the block's 180 gate rows ([gate][60 j] order) with all 19 K-chunk
// A-fragments RESIDENT in VGPRs. Gate thread t<320 (b=t/10, q=t%10) owns
// h[j0+6q..+5] of batch b: it computes the 6 gates, keeps fp32 h in
// REGISTERS, and publishes ONE 16B tagged packet {3 dwords bf16 h, tag}
// straight from registers (no LDS staging, no pre-publish barrier).
// Consumers poll <=4 packets each; 16B store/load = single LLC transaction
// so a matching tag certifies the h in the same load. 8-slot ring, lag <= 1.
#define GRP 5
#define RSLOT 8
#define NPKT 1600            // per dir: 300 j * 32 b / 6
#define HBUF_DWORDS (2 * RSLOT * NPKT * 4)

__global__ __launch_bounds__(512, 1) void gru_layer(
        const float* __restrict__ xp_all, // [2 dir][400][32][900] contiguous
        const ushort_t* __restrict__ wbf, // [2 dir][900][300] bf16, this layer
        const float* __restrict__ bhh,    // [2 dir][900], this layer
        uint_t* __restrict__ hbuf,        // shared packet ring
        int layer,
        float* __restrict__ out) {        // [400][32][600]
    int dir = blockIdx.x / GRP;
    int bi  = blockIdx.x - dir * GRP;
    int j0  = bi * 60;
    const float* xp = xp_all + (size_t)dir * (400 * 32 * 900);
    int tid = threadIdx.x;
    int lane = tid & 63;
    int wv = tid >> 6;                 // wave 0..7 (0-5 do MFMA)
    uint_t* hb_dir = hbuf + (size_t)dir * (RSLOT * NPKT * 4);

    __shared__ __align__(16) ushort_t sh2[32][312]; // h bf16 [batch][k]
    __shared__ float sgh[180][33];    // gh f32 [block row][batch]

    for (int i = tid; i < 32 * 156; i += 512) ((uint_t*)sh2)[i] = 0u;

    // A-fragments resident: wave wv owns block rows wv*32 .. +31
    // (block row r -> gate g=r/60, j_local=r%60 -> weight row g*300+j0+jl)
    short8 afrag[19];
    if (wv < 6) {
        int m = lane & 31, half = lane >> 5;
        int r = wv * 32 + m;
        if (r < 180) {
            int g = r / 60, jl = r - g * 60;
            const ushort_t* wrow = wbf + (size_t)dir * 270000
                                   + (size_t)(g * 300 + j0 + jl) * 300;
            for (int c = 0; c < 19; c++) {
                int k0 = c * 16 + half * 8;
                short8 f;
                #pragma unroll
                for (int e = 0; e < 8; e++) {
                    int k = k0 + e;
                    f[e] = (short)((k < 300) ? wrow[k] : (ushort_t)0);
                }
                afrag[c] = f;
            }
        } else {
            #pragma unroll
            for (int c = 0; c < 19; c++) afrag[c] = short8(0);
        }
    }

    // poll assignment: <=4 packets per thread
    int pollP[4] = {0, 0, 0, 0}, polldst[4] = {0, 0, 0, 0};
    int npoll = 0;
    for (int k = 0; k < 4; k++) {
        int P = tid + 512 * k;
        if (P < NPKT) {
            pollP[npoll] = P;
            int pbi = P / 320, rem = P - pbi * 320;
            int pb = rem / 10, pq = rem - pb * 10;
            polldst[npoll] = pb * 156 + pbi * 30 + 3 * pq;
            npoll++;
        }
    }
    // gate ownership (t<320): b=t/10, q=t%10 -> h[j0+6q..+5] of batch b
    int gb = tid / 10, gq = tid - (tid / 10) * 10;
    float hprev[6] = {0.f, 0.f, 0.f, 0.f, 0.f, 0.f};
    float br_[6], bz_[6], bn_[6];
    if (tid < 320) {
        #pragma unroll
        for (int i = 0; i < 6; i++) {
            int jj = j0 + gq * 6 + i;
            br_[i] = bhh[dir * 900 + jj];
            bz_[i] = bhh[dir * 900 + 300 + jj];
            bn_[i] = bhh[dir * 900 + 600 + jj];
        }
    }
    __syncthreads();

    for (int s = 0; s < PP; s++) {
        int te = dir ? (PP - 1 - s) : s;
        // xp prefetch (independent of h; overlaps the poll)
        float xrv[6], xzv[6], xnv[6];
        if (tid < 320) {
            const float* base = xp + ((size_t)te * 32 + gb) * 900 + j0 + gq * 6;
            #pragma unroll
            for (int u = 0; u < 3; u++) {
                *(float2*)&xrv[2 * u] = *(const float2*)(base + 2 * u);
                *(float2*)&xzv[2 * u] = *(const float2*)(base + 300 + 2 * u);
                *(float2*)&xnv[2 * u] = *(const float2*)(base + 600 + 2 * u);
            }
        }
        // poll tagged packets for h(s); unpack into sh2
        if (s > 0) {
            uint_t want = (uint_t)(layer * 1024 + s);
            const uint_t* base = hb_dir + (size_t)(s & 7) * (NPKT * 4);
            uintx4 val[4];
            int pend = (1 << npoll) - 1;
            uint_t* shdw = (uint_t*)sh2;
            while (pend) {
                #pragma unroll
                for (int k = 0; k < 4; k++) {
                    if (pend & (1 << k)) {
                        const uint_t* a = base + (size_t)pollP[k] * 4;
                        asm volatile(
                            "global_load_dwordx4 %0, %1, off sc0 sc1"
                            : "=&v"(val[k]) : "v"(a) : "memory");
                    }
                }
                asm volatile("s_waitcnt vmcnt(0)" ::: "memory");
                #pragma unroll
                for (int k = 0; k < 4; k++) {
                    if ((pend & (1 << k)) && val[k].w == want) {
                        pend &= ~(1 << k);
                        shdw[polldst[k] + 0] = val[k].x;
                        shdw[polldst[k] + 1] = val[k].y;
                        shdw[polldst[k] + 2] = val[k].z;
                    }
                }
            }
        }
        __syncthreads();                       // B1: sh2 complete
        // MFMA: waves 0-5, A resident, B from LDS; 2 independent acc chains
        if (wv < 6) {
            floatx16 a0, a1;
            #pragma unroll
            for (int r = 0; r < 16; r++) { a0[r] = 0.f; a1[r] = 0.f; }
            int n = lane & 31, half = lane >> 5;
            #pragma unroll
            for (int c = 0; c < 18; c += 2) {
                short8 bf0 = *(const short8*)&sh2[n][c * 16 + half * 8];
                a0 = __builtin_amdgcn_mfma_f32_32x32x16_bf16(
                    afrag[c], bf0, a0, 0, 0, 0);
                short8 bf1 = *(const short8*)&sh2[n][(c + 1) * 16 + half * 8];
                a1 = __builtin_amdgcn_mfma_f32_32x32x16_bf16(
                    afrag[c + 1], bf1, a1, 0, 0, 0);
            }
            {
                short8 bf0 = *(const short8*)&sh2[n][18 * 16 + half * 8];
                a0 = __builtin_amdgcn_mfma_f32_32x32x16_bf16(
                    afrag[18], bf0, a0, 0, 0, 0);
            }
            // C/D: col=lane&31, row=(r&3)+8*(r>>2)+4*(lane>>5)
            int col = lane & 31, rbase = 4 * (lane >> 5);
            #pragma unroll
            for (int r = 0; r < 16; r++) {
                int row = (r & 3) + 8 * (r >> 2) + rbase;
                int grow = wv * 32 + row;
                if (grow < 180) sgh[grow][col] = a0[r] + a1[r];
            }
        }
        __syncthreads();                       // B2: sgh complete
        // gates from registers; publish packet straight from registers
        if (tid < 320) {
            float houts[6];
            uint_t pk[3];
            #pragma unroll
            for (int i = 0; i < 6; i++) {
                int jl = gq * 6 + i;
                float ghr = sgh[jl][gb];
                float ghz = sgh[60 + jl][gb];
                float ghn = sgh[120 + jl][gb];
                float r = 1.f / (1.f + expf(-(xrv[i] + ghr + br_[i])));
                float z = 1.f / (1.f + expf(-(xzv[i] + ghz + bz_[i])));
                float n = tanhf(xnv[i] + r * (ghn + bn_[i]));
                float h = (1.f - z) * n + z * hprev[i];
                hprev[i] = h;
                houts[i] = h;
            }
            #pragma unroll
            for (int u = 0; u < 3; u++) {
                uint_t u0 = __float_as_uint(houts[2 * u]);
                u0 = (u0 + 0x7fffu + ((u0 >> 16) & 1u)) >> 16;
                uint_t u1 = __float_as_uint(houts[2 * u + 1]);
                u1 = (u1 + 0x7fffu + ((u1 >> 16) & 1u)) >> 16;
                pk[u] = u0 | (u1 << 16);
            }
            uintx4 pkt;
            pkt.x = pk[0]; pkt.y = pk[1]; pkt.z = pk[2];
            pkt.w = (uint_t)(layer * 1024 + s + 1);
            uint_t* pa = hb_dir + (size_t)((s + 1) & 7) * (NPKT * 4)
                         + (size_t)(bi * 320 + tid) * 4;
            asm volatile("global_store_dwordx4 %0, %1, off sc0 sc1"
                         :: "v"(pa), "v"(pkt) : "memory");
            // out stores after the publish (off the handoff critical path)
            float* ob = out + ((size_t)te * 32 + gb) * 600 + dir * 300
                        + j0 + gq * 6;
            *(float2*)(ob + 0) = make_float2(houts[0], houts[1]);
            *(float2*)(ob + 2) = make_float2(houts[2], houts[3]);
            *(float2*)(ob + 4) = make_float2(houts[4], houts[5]);
        }
    }
}

// ---------------------------------------------------------------------------
__global__ void span_score(const float* __restrict__ stt,
                           const float* __restrict__ endv,
                           const float* __restrict__ w_a,
                           const int* __restrict__ p_lens,
                           float* __restrict__ final_) {
    int blk = blockIdx.x;          // p*BB + b
    int p = blk / BB, b = blk - p * BB;
    __shared__ float ss[FF];
    __shared__ float wa[FF];
    for (int f = threadIdx.x; f < FF; f += blockDim.x) {
        ss[f] = stt[(size_t)(p * BB + b) * FF + f];
        wa[f] = w_a[f];
    }
    __syncthreads();
    int lane = threadIdx.x & 63, wv = threadIdx.x >> 6;
    int plen = p_lens[b];
    for (int j = wv; j < AA; j += 2) {
        float acc = 0.f;
        int pe = p + j;
        if (pe < PP) {
            const float* ev = endv + (size_t)(pe * BB + b) * FF;
            for (int f = lane; f < FF; f += 64)
                acc += fmaxf(ss[f] + ev[f], 0.f) * wa[f];
        } else {
            for (int f = lane; f < FF; f += 64)
                acc += fmaxf(ss[f], 0.f) * wa[f];
        }
        #pragma unroll
        for (int off = 32; off; off >>= 1) acc += __shfl_down(acc, off);
        if (lane == 0) {
            float v = (pe < plen) ? acc : 0.f;
            final_[(size_t)b * (PP * AA) + p * AA + j] = v;
        }
    }
}

// ---------------------------------------------------------------------------
__global__ void log_softmax_rows(float* __restrict__ out,
                                 const float* __restrict__ final_, int n) {
    int b = blockIdx.x;
    const float* row = final_ + (size_t)b * n;
    __shared__ float red[256];
    float m = -INFINITY;
    for (int i = threadIdx.x; i < n; i += 256) m = fmaxf(m, row[i]);
    red[threadIdx.x] = m;
    __syncthreads();
    for (int s = 128; s; s >>= 1) {
        if (threadIdx.x < s) red[threadIdx.x] = fmaxf(red[threadIdx.x], red[threadIdx.x + s]);
        __syncthreads();
    }
    m = red[0];
    __syncthreads();
    float sum = 0.f;
    for (int i = threadIdx.x; i < n; i += 256) sum += expf(row[i] - m);
    red[threadIdx.x] = sum;
    __syncthreads();
    for (int s = 128; s; s >>= 1) {
        if (threadIdx.x < s) red[threadIdx.x] += red[threadIdx.x + s];
        __syncthreads();
    }
    float lse = m + logf(red[0]);
    for (int i = threadIdx.x; i < n; i += 256) out[(size_t)b * n + i] = row[i] - lse;
}

// ---------------------------------------------------------------------------
extern "C" void kernel_launch(void* const* d_in, const int* in_sizes, int n_in,
                              void* d_out, int out_size, void* d_ws, size_t ws_size,
                              hipStream_t stream) {
    (void)in_sizes; (void)n_in; (void)out_size; (void)ws_size;
    const int*   p_tok  = (const int*)d_in[0];
    const int*   q_tok  = (const int*)d_in[1];
    const float* p_mask = (const float*)d_in[2];
    const float* q_mask = (const float*)d_in[3];
    const int*   p_lens = (const int*)d_in[4];
    const float* embed   = (const float*)d_in[6];
    const float* w_align = (const float*)d_in[7];
    const float* b_align = (const float*)d_in[8];
    const float* w_ih    = (const float*)d_in[9];    // [2,2,900,600]
    const float* w_hh    = (const float*)d_in[10];   // [2,2,900,300]
    const float* b_ih    = (const float*)d_in[11];   // [2,2,900]
    const float* b_hh    = (const float*)d_in[12];   // [2,2,900]
    const float* w_stt   = (const float*)d_in[13];
    const float* b_stt   = (const float*)d_in[14];
    const float* w_end   = (const float*)d_in[15];
    const float* b_end   = (const float*)d_in[16];
    const float* w_a     = (const float*)d_in[17];
    float* out = (float*)d_out;
    float* ws = (float*)d_ws;

    size_t off = 0;
    float* p_emb = ws + off;  off += (size_t)PP * BB * EE;       // 3,840,000
    float* ff_p  = ws + off;  off += (size_t)PP * BB * FF;       // 3,840,000
    float* q_emb = ws + off;  off += (size_t)QQ * BB * EE;       //   288,000
    float* ff_q  = ws + off;  off += (size_t)QQ * BB * FF;       //   288,000
    float* scores= ws + off;  off += (size_t)BB * PP * QQ;       //   384,000
    float* x0    = ws + off;  off += (size_t)PP * BB * 2 * EE;   // 7,680,000
    float* xp_f  = ws + off;  off += (size_t)PP * BB * 900;      // 11,520,000
    float* xp_b  = ws + off;  off += (size_t)PP * BB * 900;      // 11,520,000  (contiguous after xp_f)
    ushort_t* wbf = (ushort_t*)(ws + off); off += 540000;        // 4*900*300 bf16
    uint_t* hbuf = (uint_t*)(ws + off); off += HBUF_DWORDS;      // packet ring
    float* x1    = p_emb;       // aliases p_emb+ff_p (dead by GRU time)
    float* sttb  = xp_f;        // aliases xp (dead after layer-2 recurrence)
    float* endb  = xp_f + (size_t)PP * BB * FF;
    float* finalb= scores;

    const int M = PP * BB;      // 12800
    const int Mq = QQ * BB;     // 960

    // prep: bf16 recurrent weights (packet ring needs NO init: 0xAA poison
    // and cross-layer tags can never equal a live tag)
    convert_whh_bf16<<<(4 * 900 * 300 + 255) / 256, 256, 0, stream>>>(w_hh, wbf);

    // 1. embedding gathers
    gather_embed<<<(M * EE + 255) / 256, 256, 0, stream>>>(p_tok, embed, p_emb, M);
    gather_embed<<<(Mq * EE + 255) / 256, 256, 0, stream>>>(q_tok, embed, q_emb, Mq);

    // 2. aligned-attention projections (relu)
    gemm_nt_bias<<<dim3((FF + BN - 1) / BN, (M + BM - 1) / BM), 256, 0, stream>>>(
        p_emb, w_align, b_align, ff_p, M, FF, EE, 1);
    gemm_nt_bias<<<dim3((FF + BN - 1) / BN, (Mq + BM - 1) / BM), 256, 0, stream>>>(
        q_emb, w_align, b_align, ff_q, Mq, FF, EE, 1);

    // 3. scores + softmax over q
    scores_softmax<<<PP * BB, 64, 0, stream>>>(ff_p, ff_q, p_mask, q_mask, scores);

    // 4. q_align + concat -> x0 = p_star [P,B,600]
    align_concat<<<PP * BB, 256, 0, stream>>>(scores, q_emb, p_emb, x0);

    // 5. BiGRU, 2 layers: batched xp GEMMs + one persistent MFMA kernel/layer
    for (int l = 0; l < LL; l++) {
        const float* xin = (l == 0) ? x0 : x1;
        float* xout = (l == 0) ? x1 : x0;
        gemm_nt_bias<<<dim3((900 + BN - 1) / BN, (M + BM - 1) / BM), 256, 0, stream>>>(
            xin, w_ih + (size_t)(l * 2 + 0) * 900 * 600, b_ih + (l * 2 + 0) * 900,
            xp_f, M, 900, 600, 0);
        gemm_nt_bias<<<dim3((900 + BN - 1) / BN, (M + BM - 1) / BM), 256, 0, stream>>>(
            xin, w_ih + (size_t)(l * 2 + 1) * 900 * 600, b_ih + (l * 2 + 1) * 900,
            xp_b, M, 900, 600, 0);
        gru_layer<<<2 * GRP, 512, 0, stream>>>(
            xp_f,
            wbf + (size_t)l * 2 * 270000,
            b_hh + (size_t)l * 2 * 900,
            hbuf, l, xout);
    }

    // 6. stt / end projections (relu) from layer-2 output (in x0)
    gemm_nt_bias<<<dim3((FF + BN - 1) / BN, (M + BM - 1) / BM), 256, 0, stream>>>(
        x0, w_stt, b_stt, sttb, M, FF, 2 * HH, 1);
    gemm_nt_bias<<<dim3((FF + BN - 1) / BN, (M + BM - 1) / BM), 256, 0, stream>>>(
        x0, w_end, b_end, endb, M, FF, 2 * HH, 1);

    // 7. span scores
    span_score<<<PP * BB, 128, 0, stream>>>(sttb, endb, w_a, p_lens, finalb);

    // 8. log-softmax rows -> out
    log_softmax_rows<<<BB, 256, 0, stream>>>(out, finalb, PP * AA);
}

// Round 8
// 3831.612 us; speedup vs baseline: 2.7648x; 1.2329x over previous
//
#include <hip/hip_runtime.h>
#include <hip/hip_bf16.h>
#include <math.h>

// Problem dims
#define PP 400
#define QQ 30
#define BB 32
#define EE 300
#define HH 300
#define FF 300
#define AA 30
#define LL 2

typedef unsigned short ushort_t;
typedef unsigned int uint_t;
typedef __attribute__((ext_vector_type(8))) short short8;
typedef __attribute__((ext_vector_type(16))) float floatx16;
typedef __attribute__((ext_vector_type(4))) uint_t uintx4;

__device__ __forceinline__ uint_t f2bf(float f) {
    uint_t u = __float_as_uint(f);
    return (u + 0x7fffu + ((u >> 16) & 1u)) >> 16;
}
__device__ __forceinline__ float bf2f(ushort_t v) {
    return __uint_as_float(((uint_t)v) << 16);
}

// ---------------------------------------------------------------------------
// Embedding gather -> bf16 with K padded 300->304 (pad zeroed)
__global__ void gather_embed_bf(const int* __restrict__ tok,
                                const float* __restrict__ embed,
                                ushort_t* __restrict__ out, int n_tok) {
    int i = blockIdx.x * blockDim.x + threadIdx.x;
    int n = n_tok * 304;
    if (i >= n) return;
    int row = i / 304, e = i - row * 304;
    out[i] = (e < EE) ? (ushort_t)f2bf(embed[(size_t)tok[row] * EE + e]) : 0;
}

// fp32 [R][K] -> bf16 [R][KP], zero pad
__global__ void convert_pad_bf16(const float* __restrict__ src,
                                 ushort_t* __restrict__ dst,
                                 int R, int K, int KP) {
    int i = blockIdx.x * blockDim.x + threadIdx.x;
    if (i >= R * KP) return;
    int r = i / KP, k = i - r * KP;
    dst[i] = (k < K) ? (ushort_t)f2bf(src[(size_t)r * K + k]) : 0;
}

// ---------------------------------------------------------------------------
// MFMA bf16 GEMM: C[M,N] = A[M,KP] @ B[N,KP]^T + bias[N], optional relu.
// 64x64 tile, 256 threads = 4 waves, one 32x32x16 MFMA per wave per K-chunk.
// M must be a multiple of 64; N guarded.
__global__ __launch_bounds__(256) void gemm_bf16_nt(
        const ushort_t* __restrict__ A, const ushort_t* __restrict__ B,
        const float* __restrict__ bias, float* __restrict__ C,
        int M, int N, int KP, int relu) {
    __shared__ __align__(16) ushort_t As[64][16];
    __shared__ __align__(16) ushort_t Bs[64][16];
    int tid = threadIdx.x;
    int m0 = blockIdx.y * 64, n0 = blockIdx.x * 64;
    int lane = tid & 63, wv = tid >> 6;
    int wm = wv >> 1, wn = wv & 1;
    // staging role: tid<128 -> A tile, else B tile; 2 threads per row (8 bf16 each)
    int tile = tid >> 7;
    int trow = (tid & 127) >> 1;
    int tkof = (tid & 1) * 8;
    floatx16 acc;
    #pragma unroll
    for (int r = 0; r < 16; r++) acc[r] = 0.f;

    for (int k0 = 0; k0 < KP; k0 += 16) {
        short8 v;
        if (tile == 0) {
            v = *(const short8*)(A + (size_t)(m0 + trow) * KP + k0 + tkof);
        } else {
            int br = n0 + trow;
            if (br < N)
                v = *(const short8*)(B + (size_t)br * KP + k0 + tkof);
            else
                v = short8(0);
        }
        __syncthreads();   // previous iteration's LDS reads complete
        if (tile == 0) *(short8*)&As[trow][tkof] = v;
        else           *(short8*)&Bs[trow][tkof] = v;
        __syncthreads();
        short8 af = *(const short8*)&As[wm * 32 + (lane & 31)][(lane >> 5) * 8];
        short8 bf = *(const short8*)&Bs[wn * 32 + (lane & 31)][(lane >> 5) * 8];
        acc = __builtin_amdgcn_mfma_f32_32x32x16_bf16(af, bf, acc, 0, 0, 0);
    }
    // C/D: col = lane&31, row = (r&3) + 8*(r>>2) + 4*(lane>>5)
    int col = n0 + wn * 32 + (lane & 31);
    if (col < N) {
        float bv = bias[col];
        int rbase = m0 + wm * 32 + 4 * (lane >> 5);
        #pragma unroll
        for (int r = 0; r < 16; r++) {
            int row = rbase + (r & 3) + 8 * (r >> 2);
            float v = acc[r] + bv;
            if (relu) v = fmaxf(v, 0.f);
            C[(size_t)row * N + col] = v;
        }
    }
}

// ---------------------------------------------------------------------------
// scores + softmax over q per (p,b)  (ff_p/ff_q fp32 from MFMA GEMM)
__global__ void scores_softmax(const float* __restrict__ ffp,
                               const float* __restrict__ ffq,
                               const float* __restrict__ p_mask,
                               const float* __restrict__ q_mask,
                               float* __restrict__ weights) {
    int blk = blockIdx.x;          // p*BB + b
    int p = blk / BB, b = blk - p * BB;
    __shared__ float fp[FF];
    __shared__ float sq[QQ];
    for (int f = threadIdx.x; f < FF; f += blockDim.x)
        fp[f] = ffp[(size_t)(p * BB + b) * FF + f];
    __syncthreads();
    int q = threadIdx.x;
    if (q < QQ) {
        const float* fq = ffq + (size_t)(q * BB + b) * FF;
        float s = 0.f;
        for (int f = 0; f < FF; f++) s += fp[f] * fq[f];
        s *= p_mask[p * BB + b] * q_mask[q * BB + b];
        sq[q] = s;
    }
    __syncthreads();
    if (q < QQ) {
        float m = -INFINITY;
        for (int k = 0; k < QQ; k++) m = fmaxf(m, sq[k]);
        float sum = 0.f;
        for (int k = 0; k < QQ; k++) sum += expf(sq[k] - m);
        weights[(size_t)b * PP * QQ + p * QQ + q] = expf(sq[q] - m) / sum;
    }
}

// ---------------------------------------------------------------------------
// x0BF[p][b][0:300] = p_embBF; [300:600] = bf16(sum_q w*q_emb). Stride 608.
__global__ void align_concat_bf(const float* __restrict__ weights,
                                const ushort_t* __restrict__ q_embBF,
                                const ushort_t* __restrict__ p_embBF,
                                ushort_t* __restrict__ x0BF) {
    int blk = blockIdx.x;          // p*BB + b
    int p = blk / BB, b = blk - p * BB;
    __shared__ float w[QQ];
    if (threadIdx.x < QQ)
        w[threadIdx.x] = weights[(size_t)b * PP * QQ + p * QQ + threadIdx.x];
    __syncthreads();
    size_t obase = (size_t)(p * BB + b) * 608;
    for (int e = threadIdx.x; e < EE; e += blockDim.x) {
        float acc = 0.f;
        for (int q = 0; q < QQ; q++)
            acc += w[q] * bf2f(q_embBF[(size_t)(q * BB + b) * 304 + e]);
        x0BF[obase + e] = p_embBF[(size_t)(p * BB + b) * 304 + e];
        x0BF[obase + EE + e] = (ushort_t)f2bf(acc);
    }
}

// ---------------------------------------------------------------------------
// w_hh fp32 [4][900][300] -> bf16 (RNE) same layout (GRU A-fragments)
__global__ void convert_whh_bf16(const float* __restrict__ w,
                                 ushort_t* __restrict__ o) {
    int i = blockIdx.x * blockDim.x + threadIdx.x;
    if (i >= 4 * 900 * 300) return;
    o[i] = (ushort_t)f2bf(w[i]);
}

// ---------------------------------------------------------------------------
// Persistent BiGRU layer, MFMA recurrence, TAGGED-PACKET handoff (R7 struct).
// R8 change: `out` is bf16 [400][32][608] (pad pre-zeroed by memset) — the
// packet bf16 packs are reused for the out store (12 B/thread vs 24 B).
#define GRP 5
#define RSLOT 8
#define NPKT 1600            // per dir: 300 j * 32 b / 6
#define HBUF_DWORDS (2 * RSLOT * NPKT * 4)

__global__ __launch_bounds__(512, 1) void gru_layer(
        const float* __restrict__ xp_all, // [2 dir][400][32][900] contiguous
        const ushort_t* __restrict__ wbf, // [2 dir][900][300] bf16, this layer
        const float* __restrict__ bhh,    // [2 dir][900], this layer
        uint_t* __restrict__ hbuf,        // shared packet ring
        int layer,
        ushort_t* __restrict__ out) {     // [400][32][608] bf16
    int dir = blockIdx.x / GRP;
    int bi  = blockIdx.x - dir * GRP;
    int j0  = bi * 60;
    const float* xp = xp_all + (size_t)dir * (400 * 32 * 900);
    int tid = threadIdx.x;
    int lane = tid & 63;
    int wv = tid >> 6;                 // wave 0..7 (0-5 do MFMA)
    uint_t* hb_dir = hbuf + (size_t)dir * (RSLOT * NPKT * 4);

    __shared__ __align__(16) ushort_t sh2[32][312]; // h bf16 [batch][k]
    __shared__ float sgh[180][33];    // gh f32 [block row][batch]

    for (int i = tid; i < 32 * 156; i += 512) ((uint_t*)sh2)[i] = 0u;

    // A-fragments resident: wave wv owns block rows wv*32 .. +31
    short8 afrag[19];
    if (wv < 6) {
        int m = lane & 31, half = lane >> 5;
        int r = wv * 32 + m;
        if (r < 180) {
            int g = r / 60, jl = r - g * 60;
            const ushort_t* wrow = wbf + (size_t)dir * 270000
                                   + (size_t)(g * 300 + j0 + jl) * 300;
            for (int c = 0; c < 19; c++) {
                int k0 = c * 16 + half * 8;
                short8 f;
                #pragma unroll
                for (int e = 0; e < 8; e++) {
                    int k = k0 + e;
                    f[e] = (short)((k < 300) ? wrow[k] : (ushort_t)0);
                }
                afrag[c] = f;
            }
        } else {
            #pragma unroll
            for (int c = 0; c < 19; c++) afrag[c] = short8(0);
        }
    }

    // poll assignment: <=4 packets per thread
    int pollP[4] = {0, 0, 0, 0}, polldst[4] = {0, 0, 0, 0};
    int npoll = 0;
    for (int k = 0; k < 4; k++) {
        int P = tid + 512 * k;
        if (P < NPKT) {
            pollP[npoll] = P;
            int pbi = P / 320, rem = P - pbi * 320;
            int pb = rem / 10, pq = rem - pb * 10;
            polldst[npoll] = pb * 156 + pbi * 30 + 3 * pq;
            npoll++;
        }
    }
    // gate ownership (t<320): b=t/10, q=t%10 -> h[j0+6q..+5] of batch b
    int gb = tid / 10, gq = tid - (tid / 10) * 10;
    float hprev[6] = {0.f, 0.f, 0.f, 0.f, 0.f, 0.f};
    float br_[6], bz_[6], bn_[6];
    if (tid < 320) {
        #pragma unroll
        for (int i = 0; i < 6; i++) {
            int jj = j0 + gq * 6 + i;
            br_[i] = bhh[dir * 900 + jj];
            bz_[i] = bhh[dir * 900 + 300 + jj];
            bn_[i] = bhh[dir * 900 + 600 + jj];
        }
    }
    __syncthreads();

    for (int s = 0; s < PP; s++) {
        int te = dir ? (PP - 1 - s) : s;
        // xp prefetch (independent of h; overlaps the poll)
        float xrv[6], xzv[6], xnv[6];
        if (tid < 320) {
            const float* base = xp + ((size_t)te * 32 + gb) * 900 + j0 + gq * 6;
            #pragma unroll
            for (int u = 0; u < 3; u++) {
                *(float2*)&xrv[2 * u] = *(const float2*)(base + 2 * u);
                *(float2*)&xzv[2 * u] = *(const float2*)(base + 300 + 2 * u);
                *(float2*)&xnv[2 * u] = *(const float2*)(base + 600 + 2 * u);
            }
        }
        // poll tagged packets for h(s); unpack into sh2
        if (s > 0) {
            uint_t want = (uint_t)(layer * 1024 + s);
            const uint_t* base = hb_dir + (size_t)(s & 7) * (NPKT * 4);
            uintx4 val[4];
            int pend = (1 << npoll) - 1;
            uint_t* shdw = (uint_t*)sh2;
            while (pend) {
                #pragma unroll
                for (int k = 0; k < 4; k++) {
                    if (pend & (1 << k)) {
                        const uint_t* a = base + (size_t)pollP[k] * 4;
                        asm volatile(
                            "global_load_dwordx4 %0, %1, off sc0 sc1"
                            : "=&v"(val[k]) : "v"(a) : "memory");
                    }
                }
                asm volatile("s_waitcnt vmcnt(0)" ::: "memory");
                #pragma unroll
                for (int k = 0; k < 4; k++) {
                    if ((pend & (1 << k)) && val[k].w == want) {
                        pend &= ~(1 << k);
                        shdw[polldst[k] + 0] = val[k].x;
                        shdw[polldst[k] + 1] = val[k].y;
                        shdw[polldst[k] + 2] = val[k].z;
                    }
                }
            }
        }
        __syncthreads();                       // B1: sh2 complete
        // MFMA: waves 0-5, A resident, B from LDS; 2 independent acc chains
        if (wv < 6) {
            floatx16 a0, a1;
            #pragma unroll
            for (int r = 0; r < 16; r++) { a0[r] = 0.f; a1[r] = 0.f; }
            int n = lane & 31, half = lane >> 5;
            #pragma unroll
            for (int c = 0; c < 18; c += 2) {
                short8 bf0 = *(const short8*)&sh2[n][c * 16 + half * 8];
                a0 = __builtin_amdgcn_mfma_f32_32x32x16_bf16(
                    afrag[c], bf0, a0, 0, 0, 0);
                short8 bf1 = *(const short8*)&sh2[n][(c + 1) * 16 + half * 8];
                a1 = __builtin_amdgcn_mfma_f32_32x32x16_bf16(
                    afrag[c + 1], bf1, a1, 0, 0, 0);
            }
            {
                short8 bf0 = *(const short8*)&sh2[n][18 * 16 + half * 8];
                a0 = __builtin_amdgcn_mfma_f32_32x32x16_bf16(
                    afrag[18], bf0, a0, 0, 0, 0);
            }
            int col = lane & 31, rbase = 4 * (lane >> 5);
            #pragma unroll
            for (int r = 0; r < 16; r++) {
                int row = (r & 3) + 8 * (r >> 2) + rbase;
                int grow = wv * 32 + row;
                if (grow < 180) sgh[grow][col] = a0[r] + a1[r];
            }
        }
        __syncthreads();                       // B2: sgh complete
        // gates from registers; publish packet straight from registers
        if (tid < 320) {
            float houts[6];
            uint_t pk[3];
            #pragma unroll
            for (int i = 0; i < 6; i++) {
                int jl = gq * 6 + i;
                float ghr = sgh[jl][gb];
                float ghz = sgh[60 + jl][gb];
                float ghn = sgh[120 + jl][gb];
                float r = 1.f / (1.f + expf(-(xrv[i] + ghr + br_[i])));
                float z = 1.f / (1.f + expf(-(xzv[i] + ghz + bz_[i])));
                float n = tanhf(xnv[i] + r * (ghn + bn_[i]));
                float h = (1.f - z) * n + z * hprev[i];
                hprev[i] = h;
                houts[i] = h;
            }
            #pragma unroll
            for (int u = 0; u < 3; u++)
                pk[u] = f2bf(houts[2 * u]) | (f2bf(houts[2 * u + 1]) << 16);
            uintx4 pkt;
            pkt.x = pk[0]; pkt.y = pk[1]; pkt.z = pk[2];
            pkt.w = (uint_t)(layer * 1024 + s + 1);
            uint_t* pa = hb_dir + (size_t)((s + 1) & 7) * (NPKT * 4)
                         + (size_t)(bi * 320 + tid) * 4;
            asm volatile("global_store_dwordx4 %0, %1, off sc0 sc1"
                         :: "v"(pa), "v"(pkt) : "memory");
            // bf16 out store (off the handoff critical path)
            uint_t* ob = (uint_t*)(out + ((size_t)te * 32 + gb) * 608
                                   + dir * 300 + j0 + gq * 6);
            ob[0] = pk[0]; ob[1] = pk[1]; ob[2] = pk[2];
        }
    }
}

// ---------------------------------------------------------------------------
__global__ void span_score(const float* __restrict__ stt,
                           const float* __restrict__ endv,
                           const float* __restrict__ w_a,
                           const int* __restrict__ p_lens,
                           float* __restrict__ final_) {
    int blk = blockIdx.x;          // p*BB + b
    int p = blk / BB, b = blk - p * BB;
    __shared__ float ss[FF];
    __shared__ float wa[FF];
    for (int f = threadIdx.x; f < FF; f += blockDim.x) {
        ss[f] = stt[(size_t)(p * BB + b) * FF + f];
        wa[f] = w_a[f];
    }
    __syncthreads();
    int lane = threadIdx.x & 63, wv = threadIdx.x >> 6;
    int plen = p_lens[b];
    for (int j = wv; j < AA; j += 2) {
        float acc = 0.f;
        int pe = p + j;
        if (pe < PP) {
            const float* ev = endv + (size_t)(pe * BB + b) * FF;
            for (int f = lane; f < FF; f += 64)
                acc += fmaxf(ss[f] + ev[f], 0.f) * wa[f];
        } else {
            for (int f = lane; f < FF; f += 64)
                acc += fmaxf(ss[f], 0.f) * wa[f];
        }
        #pragma unroll
        for (int off = 32; off; off >>= 1) acc += __shfl_down(acc, off);
        if (lane == 0) {
            float v = (pe < plen) ? acc : 0.f;
            final_[(size_t)b * (PP * AA) + p * AA + j] = v;
        }
    }
}

// ---------------------------------------------------------------------------
__global__ void log_softmax_rows(float* __restrict__ out,
                                 const float* __restrict__ final_, int n) {
    int b = blockIdx.x;
    const float* row = final_ + (size_t)b * n;
    __shared__ float red[256];
    float m = -INFINITY;
    for (int i = threadIdx.x; i < n; i += 256) m = fmaxf(m, row[i]);
    red[threadIdx.x] = m;
    __syncthreads();
    for (int s = 128; s; s >>= 1) {
        if (threadIdx.x < s) red[threadIdx.x] = fmaxf(red[threadIdx.x], red[threadIdx.x + s]);
        __syncthreads();
    }
    m = red[0];
    __syncthreads();
    float sum = 0.f;
    for (int i = threadIdx.x; i < n; i += 256) sum += expf(row[i] - m);
    red[threadIdx.x] = sum;
    __syncthreads();
    for (int s = 128; s; s >>= 1) {
        if (threadIdx.x < s) red[threadIdx.x] += red[threadIdx.x + s];
        __syncthreads();
    }
    float lse = m + logf(red[0]);
    for (int i = threadIdx.x; i < n; i += 256) out[(size_t)b * n + i] = row[i] - lse;
}

// ---------------------------------------------------------------------------
extern "C" void kernel_launch(void* const* d_in, const int* in_sizes, int n_in,
                              void* d_out, int out_size, void* d_ws, size_t ws_size,
                              hipStream_t stream) {
    (void)in_sizes; (void)n_in; (void)out_size; (void)ws_size;
    const int*   p_tok  = (const int*)d_in[0];
    const int*   q_tok  = (const int*)d_in[1];
    const float* p_mask = (const float*)d_in[2];
    const float* q_mask = (const float*)d_in[3];
    const int*   p_lens = (const int*)d_in[4];
    const float* embed   = (const float*)d_in[6];
    const float* w_align = (const float*)d_in[7];
    const float* b_align = (const float*)d_in[8];
    const float* w_ih    = (const float*)d_in[9];    // [2,2,900,600]
    const float* w_hh    = (const float*)d_in[10];   // [2,2,900,300]
    const float* b_ih    = (const float*)d_in[11];   // [2,2,900]
    const float* b_hh    = (const float*)d_in[12];   // [2,2,900]
    const float* w_stt   = (const float*)d_in[13];
    const float* b_stt   = (const float*)d_in[14];
    const float* w_end   = (const float*)d_in[15];
    const float* b_end   = (const float*)d_in[16];
    const float* w_a     = (const float*)d_in[17];
    float* out = (float*)d_out;
    float* ws = (float*)d_ws;

    // Workspace layout (float units; all offsets multiples of 4 -> 16B align)
    size_t off = 0;
    ushort_t* p_embBF = (ushort_t*)(ws + off); off += 1945600;  // 12800x304
    ushort_t* q_embBF = (ushort_t*)(ws + off); off += 145920;   // 960x304
    float* ff_p  = ws + off;  off += (size_t)12800 * 300;
    float* ff_q  = ws + off;  off += (size_t)960 * 300;
    float* scores= ws + off;  off += (size_t)BB * PP * QQ;
    ushort_t* x0BF = (ushort_t*)(ws + off); off += 3891200;     // 12800x608
    ushort_t* x1BF = (ushort_t*)(ws + off); off += 3891200;     // 12800x608
    float* xp_f  = ws + off;  off += (size_t)400 * 32 * 900;
    float* xp_b  = ws + off;  off += (size_t)400 * 32 * 900;
    ushort_t* wihBF   = (ushort_t*)(ws + off); off += 1094400;  // 4x900x608
    ushort_t* walignBF= (ushort_t*)(ws + off); off += 45600;    // 300x304
    ushort_t* wsttBF  = (ushort_t*)(ws + off); off += 91200;    // 300x608
    ushort_t* wendBF  = (ushort_t*)(ws + off); off += 91200;    // 300x608
    ushort_t* whhBF   = (ushort_t*)(ws + off); off += 540000;   // 4x900x300
    uint_t* hbuf = (uint_t*)(ws + off); off += HBUF_DWORDS;
    float* sttb  = xp_f;                        // alias (xp dead by then)
    float* endb  = xp_f + (size_t)12800 * 300;
    float* finalb= scores;

    const int M = PP * BB;      // 12800
    const int Mq = QQ * BB;     // 960

    // weight conversions (bf16, K padded)
    convert_whh_bf16<<<(4 * 900 * 300 + 255) / 256, 256, 0, stream>>>(w_hh, whhBF);
    for (int ld = 0; ld < 4; ld++)
        convert_pad_bf16<<<(900 * 608 + 255) / 256, 256, 0, stream>>>(
            w_ih + (size_t)ld * 900 * 600, wihBF + (size_t)ld * 900 * 608,
            900, 600, 608);
    convert_pad_bf16<<<(300 * 304 + 255) / 256, 256, 0, stream>>>(
        w_align, walignBF, 300, 300, 304);
    convert_pad_bf16<<<(300 * 608 + 255) / 256, 256, 0, stream>>>(
        w_stt, wsttBF, 300, 600, 608);
    convert_pad_bf16<<<(300 * 608 + 255) / 256, 256, 0, stream>>>(
        w_end, wendBF, 300, 600, 608);

    // zero x0BF/x1BF (pads must be 0 for the K-padded GEMMs)
    hipMemsetAsync(x0BF, 0, (size_t)12800 * 608 * 2, stream);
    hipMemsetAsync(x1BF, 0, (size_t)12800 * 608 * 2, stream);

    // 1. embedding gathers (bf16, padded)
    gather_embed_bf<<<(M * 304 + 255) / 256, 256, 0, stream>>>(p_tok, embed, p_embBF, M);
    gather_embed_bf<<<(Mq * 304 + 255) / 256, 256, 0, stream>>>(q_tok, embed, q_embBF, Mq);

    // 2. aligned-attention projections (relu) — MFMA bf16
    gemm_bf16_nt<<<dim3(5, 200), 256, 0, stream>>>(
        p_embBF, walignBF, b_align, ff_p, M, 300, 304, 1);
    gemm_bf16_nt<<<dim3(5, 15), 256, 0, stream>>>(
        q_embBF, walignBF, b_align, ff_q, Mq, 300, 304, 1);

    // 3. scores + softmax over q
    scores_softmax<<<PP * BB, 64, 0, stream>>>(ff_p, ff_q, p_mask, q_mask, scores);

    // 4. q_align + concat -> x0BF (bf16, stride 608)
    align_concat_bf<<<PP * BB, 256, 0, stream>>>(scores, q_embBF, p_embBF, x0BF);

    // 5. BiGRU, 2 layers: MFMA xp GEMMs + persistent MFMA recurrence
    for (int l = 0; l < LL; l++) {
        const ushort_t* xin = (l == 0) ? x0BF : x1BF;
        ushort_t* xout = (l == 0) ? x1BF : x0BF;
        gemm_bf16_nt<<<dim3(15, 200), 256, 0, stream>>>(
            xin, wihBF + (size_t)(l * 2 + 0) * 900 * 608,
            b_ih + (l * 2 + 0) * 900, xp_f, M, 900, 608, 0);
        gemm_bf16_nt<<<dim3(15, 200), 256, 0, stream>>>(
            xin, wihBF + (size_t)(l * 2 + 1) * 900 * 608,
            b_ih + (l * 2 + 1) * 900, xp_b, M, 900, 608, 0);
        gru_layer<<<2 * GRP, 512, 0, stream>>>(
            xp_f,
            whhBF + (size_t)l * 2 * 270000,
            b_hh + (size_t)l * 2 * 900,
            hbuf, l, xout);
    }

    // 6. stt / end projections (relu) from layer-2 output (x0BF)
    gemm_bf16_nt<<<dim3(5, 200), 256, 0, stream>>>(
        x0BF, wsttBF, b_stt, sttb, M, 300, 608, 1);
    gemm_bf16_nt<<<dim3(5, 200), 256, 0, stream>>>(
        x0BF, wendBF, b_end, endb, M, 300, 608, 1);

    // 7. span scores
    span_score<<<PP * BB, 128, 0, stream>>>(sttb, endb, w_a, p_lens, finalb);

    // 8. log-softmax rows -> out
    log_softmax_rows<<<BB, 256, 0, stream>>>(out, finalb, PP * AA);
}